// Round 26
// baseline (449.265 us; speedup 1.0000x reference)
//
#include <hip/hip_runtime.h>
#include <math.h>

namespace {

constexpr int Bn=2, CIc=16, COc=16, Hc=256, Wc=256, HIDc=64, C5c=320;
constexpr int SPc = 4096;               // 64*64
constexpr float EPSc = 1e-5f;

// ---- 4x4 mean downsample: x (B,16,256,256) -> xd (B,16,64,64) ----
__global__ void k_down(const float* __restrict__ x, float* __restrict__ xd){
  int idx = blockIdx.x*blockDim.x + threadIdx.x;
  if (idx >= Bn*CIc*SPc) return;
  int q = idx & 63, p = (idx>>6)&63, c = idx>>12;
  const float* xp = x + ((size_t)c*Hc + p*4)*Wc + q*4;
  float s = 0.f;
  #pragma unroll
  for(int dy=0; dy<4; dy++)
    #pragma unroll
    for(int dx=0; dx<4; dx++) s += xp[dy*Wc+dx];
  xd[idx] = s * (1.f/16.f);
}

// ---- conv0 3x3 pad1 (16->64) + scalar PReLU ----
__global__ void k_conv0(const float* __restrict__ xd, const float* __restrict__ w,
                        const float* __restrict__ bias, const float* __restrict__ a0,
                        float* __restrict__ h){
  int idx = blockIdx.x*blockDim.x + threadIdx.x;
  if (idx >= Bn*HIDc*SPc) return;
  int q = idx&63, p=(idx>>6)&63, co=(idx>>12)&63, b=idx/(HIDc*SPc);
  float acc = bias[co];
  for(int ci=0; ci<CIc; ci++){
    const float* xp = xd + (size_t)(b*CIc+ci)*SPc;
    const float* wp = w + (co*CIc+ci)*9;
    #pragma unroll
    for(int u=0; u<3; u++){
      int pp = p+u-1; if((unsigned)pp >= 64u) continue;
      #pragma unroll
      for(int v=0; v<3; v++){
        int qq = q+v-1; if((unsigned)qq >= 64u) continue;
        acc = fmaf(xp[pp*64+qq], wp[u*3+v], acc);
      }
    }
  }
  float a = a0[0];
  h[idx] = acc >= 0.f ? acc : a*acc;
}

// ---- fused 1x1 conv 64->320 + BN1 stat partials ----
__global__ void k_c1(const float* __restrict__ h, const float* __restrict__ w,
                     const float* __restrict__ bias, float* __restrict__ t1,
                     float* __restrict__ pacc){
  __shared__ float lh[64*64];
  int og = blockIdx.x, sj = blockIdx.y, b = blockIdx.z;
  int tid = threadIdx.x;
  for(int it=0; it<4; ++it){
    int f4 = tid + it*256;               // c*16 + s4
    int c = f4>>4, s4 = f4&15;
    float4 v = *(const float4*)(h + (size_t)(b*64+c)*SPc + sj*64 + s4*4);
    *(float4*)(&lh[c*64 + s4*4]) = v;
  }
  __syncthreads();
  int osub = tid>>6, s = tid&63;
  int ob = og*40 + osub*10;
  float acc[10];
  #pragma unroll
  for(int j=0;j<10;j++) acc[j] = bias[ob+j];
  for(int c=0;c<64;c++){
    float hv = lh[c*64+s];
    #pragma unroll
    for(int j=0;j<10;j++) acc[j] = fmaf(hv, w[(ob+j)*64 + c], acc[j]);
  }
  #pragma unroll
  for(int j=0;j<10;j++){
    int o = ob+j;
    t1[(size_t)(b*320+o)*SPc + sj*64 + s] = acc[j];
    float sm = acc[j], sq = acc[j]*acc[j];
    #pragma unroll
    for(int d=1; d<64; d<<=1){ sm += __shfl_xor(sm,d); sq += __shfl_xor(sq,d); }
    if(s==0){
      pacc[o*128 + b*64 + sj]         = sm;   // P=128
      pacc[40960 + o*128 + b*64 + sj] = sq;   // CP = 320*128
    }
  }
}

// ---- finalize (out-BN only): partials -> A,B ----
__global__ void k_fin(const float* __restrict__ pacc, int P, float invN,
                      const float* __restrict__ g, const float* __restrict__ bb,
                      float* __restrict__ A, float* __restrict__ B){
  __shared__ double sh[256], sh2[256];
  int c = blockIdx.x, C = gridDim.x, tid = threadIdx.x;
  double s=0.0, s2=0.0;
  for(int p=tid; p<P; p+=256){
    s  += (double)pacc[c*P+p];
    s2 += (double)pacc[C*P + c*P + p];
  }
  sh[tid]=s; sh2[tid]=s2; __syncthreads();
  for(int off=128; off>0; off>>=1){
    if(tid<off){ sh[tid]+=sh[tid+off]; sh2[tid]+=sh2[tid+off]; }
    __syncthreads();
  }
  if(tid==0){
    float m = (float)(sh[0]*(double)invN);
    float v = (float)(sh2[0]*(double)invN) - m*m;
    float r = rsqrtf(v + EPSc);
    float gc = g[c];
    A[c] = gc*r;
    B[c] = bb[c] - m*gc*r;
  }
}

// ---- depthwise 3x3; BN1 finalized in prologue; BN2 partials out ----
__global__ void k_dw_s(const float* __restrict__ t1, const float* __restrict__ w,
                       const float* __restrict__ bias, const float* __restrict__ g1,
                       const float* __restrict__ bb1, const float* __restrict__ ap,
                       const float* __restrict__ pin, float* __restrict__ t2,
                       float* __restrict__ pout){
  int tid = threadIdx.x;
  int idx = blockIdx.x*256 + tid;
  int q = idx&63, p=(idx>>6)&63, c=(idx>>12)%C5c, b=idx/(C5c*SPc);
  __shared__ float sAB[2];
  __shared__ float ws4[4];
  {
    float v = (tid<128) ? pin[c*128 + tid] : pin[40960 + c*128 + (tid-128)];
    #pragma unroll
    for(int d=1; d<64; d<<=1) v += __shfl_xor(v, d);
    int wv = tid>>6, ln = tid&63;
    if(ln==0) ws4[wv] = v;
    __syncthreads();
    if(tid==0){
      float S = ws4[0]+ws4[1], Q = ws4[2]+ws4[3];
      float m = S*(1.f/8192.f);
      float var = Q*(1.f/8192.f) - m*m;
      float r = rsqrtf(var + EPSc);
      float gc = g1[c];
      sAB[0] = gc*r; sAB[1] = bb1[c] - m*gc*r;
    }
    __syncthreads();
  }
  float a1 = sAB[0], b1 = sAB[1], al = ap[0];
  const float* ip = t1 + (size_t)(b*C5c+c)*SPc;
  const float* wp = w + c*9;
  float acc = bias[c];
  #pragma unroll
  for(int u=0; u<3; u++){
    int pp = p+u-1; if((unsigned)pp >= 64u) continue;
    #pragma unroll
    for(int v=0; v<3; v++){
      int qq = q+v-1; if((unsigned)qq >= 64u) continue;
      float y = fmaf(ip[pp*64+qq], a1, b1);
      y = y >= 0.f ? y : al*y;
      acc = fmaf(y, wp[u*3+v], acc);
    }
  }
  t2[idx] = acc;
  float sm = acc, sq = acc*acc;
  #pragma unroll
  for(int d=1; d<64; d<<=1){ sm += __shfl_xor(sm,d); sq += __shfl_xor(sq,d); }
  __shared__ float sred[8];
  int wv = tid>>6, ln = tid&63;
  if(ln==0){ sred[wv]=sm; sred[4+wv]=sq; }
  __syncthreads();
  if(tid==0){
    float S = ((sred[0]+sred[1])+(sred[2]+sred[3]));
    float Q = ((sred[4]+sred[5])+(sred[6]+sred[7]));
    int j = blockIdx.x & 15;
    pout[c*32 + b*16 + j]         = S;   // P=32
    pout[10240 + c*32 + b*16 + j] = Q;   // CP = 320*32
  }
}

// ---- full-K 1x1 conv 320->64; BN2 finalized in prologue; BN3 partials out ----
__global__ void k_c3f(const float* __restrict__ t2, const float* __restrict__ w,
                      const float* __restrict__ bias, const float* __restrict__ g2,
                      const float* __restrict__ bb2, const float* __restrict__ ap,
                      const float* __restrict__ pin, float* __restrict__ ts,
                      float* __restrict__ pout){
  __shared__ float sA[320], sB[320];
  __shared__ float li[320*16];    // 20 KB
  int sjf = blockIdx.x, b = blockIdx.y;
  int tid = threadIdx.x;
  for(int c = tid; c < 320; c += 256){
    const float4* ps = (const float4*)(pin + c*32);
    const float4* pq = (const float4*)(pin + 10240 + c*32);
    float S=0.f, Q=0.f;
    #pragma unroll
    for(int j=0;j<8;j++){ float4 a = ps[j]; S += ((a.x+a.y)+(a.z+a.w)); }
    #pragma unroll
    for(int j=0;j<8;j++){ float4 a = pq[j]; Q += ((a.x+a.y)+(a.z+a.w)); }
    float m = S*(1.f/8192.f);
    float var = Q*(1.f/8192.f) - m*m;
    float r = rsqrtf(var + EPSc);
    float gc = g2[c];
    sA[c] = gc*r; sB[c] = bb2[c] - m*gc*r;
  }
  __syncthreads();
  float al = ap[0];
  for(int t = tid; t < 1280; t += 256){
    int c = t>>2, k4 = t&3;
    float4 v = *(const float4*)(t2 + (size_t)(b*C5c+c)*SPc + sjf*16 + k4*4);
    float a1 = sA[c], b1 = sB[c];
    float4 y;
    y.x = fmaf(v.x, a1, b1); y.x = y.x>=0.f ? y.x : al*y.x;
    y.y = fmaf(v.y, a1, b1); y.y = y.y>=0.f ? y.y : al*y.y;
    y.z = fmaf(v.z, a1, b1); y.z = y.z>=0.f ? y.z : al*y.z;
    y.w = fmaf(v.w, a1, b1); y.w = y.w>=0.f ? y.w : al*y.w;
    *(float4*)(&li[c*16 + k4*4]) = y;
  }
  __syncthreads();
  int og = tid>>4, s = tid&15;
  float acc[4];
  #pragma unroll
  for(int j=0;j<4;j++) acc[j] = bias[og*4+j];
  const float* wb = w + (size_t)(og*4)*C5c;
  for(int c=0; c<320; c++){
    float hv = li[c*16 + s];
    #pragma unroll
    for(int j=0;j<4;j++)
      acc[j] = fmaf(hv, wb[j*C5c + c], acc[j]);
  }
  #pragma unroll
  for(int j=0;j<4;j++){
    int o = og*4+j;
    ts[(size_t)(b*64+o)*SPc + sjf*16 + s] = acc[j];
    float sm = acc[j], sq = acc[j]*acc[j];
    #pragma unroll
    for(int d=1; d<16; d<<=1){ sm += __shfl_xor(sm,d); sq += __shfl_xor(sq,d); }
    if(s==0){
      pout[o*512 + b*256 + sjf]         = sm;  // P=512
      pout[32768 + o*512 + b*256 + sjf] = sq;  // CP = 64*512
    }
  }
}

// ---- BN3 (finalized in prologue, P=512) + PReLU3 + residual add into h ----
__global__ void k_addres(const float* __restrict__ ts, float* __restrict__ h,
                         const float* __restrict__ g3, const float* __restrict__ bb3,
                         const float* __restrict__ ap, const float* __restrict__ pin){
  int tid = threadIdx.x;
  int idx = blockIdx.x*256 + tid;
  int c = (idx>>12)&63;              // constant per block
  __shared__ float sAB[2];
  __shared__ float w8[8];
  {
    float S = pin[c*512 + tid] + pin[c*512 + 256 + tid];
    float Q = pin[32768 + c*512 + tid] + pin[32768 + c*512 + 256 + tid];
    #pragma unroll
    for(int d=1; d<64; d<<=1){ S += __shfl_xor(S,d); Q += __shfl_xor(Q,d); }
    int wv = tid>>6, ln = tid&63;
    if(ln==0){ w8[wv] = S; w8[4+wv] = Q; }
    __syncthreads();
    if(tid==0){
      float Sa = (w8[0]+w8[1])+(w8[2]+w8[3]);
      float Qa = (w8[4]+w8[5])+(w8[6]+w8[7]);
      float m = Sa*(1.f/8192.f);
      float var = Qa*(1.f/8192.f) - m*m;
      float r = rsqrtf(var + EPSc);
      float gc = g3[c];
      sAB[0] = gc*r; sAB[1] = bb3[c] - m*gc*r;
    }
    __syncthreads();
  }
  float y = fmaf(ts[idx], sAB[0], sAB[1]);
  float al = ap[0];
  y = y >= 0.f ? y : al*y;
  h[idx] += y;
}

// ---- head v2: 1x1 conv (64->512) -> gvol [b][q][ci][k][o][z=p] ----
__global__ void k_head_t(const float* __restrict__ h, const float* __restrict__ w,
                         const float* __restrict__ bias, float* __restrict__ gv){
  __shared__ float lh[8*65];      // [p8][kc64]
  __shared__ float lw[64*65];     // [cc64][kc64]
  int bid = blockIdx.x;           // (b*64 + q)*8 + pgg
  int pgg = bid & 7, q = (bid>>3) & 63, b = bid >> 9;
  int tid = threadIdx.x;
  for(int t = tid; t < 512; t += 256){
    int p = t >> 6, kc = t & 63;
    lh[p*65 + kc] = h[((size_t)(b*64+kc))*SPc + (pgg*8+p)*64 + q];
  }
  int cc = tid & 63, pp = tid >> 6;     // wave-uniform pp
  float* gb = gv + (size_t)b*(64*16*2048) + ((size_t)q*16)*2048;
  for(int ch = 0; ch < 8; ++ch){
    __syncthreads();
    for(int t = tid; t < 1024; t += 256){
      int rc = t >> 4, f4 = t & 15;
      int combo = ch*64 + rc;
      int ci = combo>>5, kk = (combo>>4)&1, o = combo&15;
      int c0 = (o*16+ci)*2 + kk;
      float4 v = *(const float4*)(w + (size_t)c0*64 + f4*4);
      *(float4*)(&lw[rc*65 + f4*4]) = v;
    }
    __syncthreads();
    int combo = ch*64 + cc;
    int ci = combo>>5, kk = (combo>>4)&1, o = combo&15;
    int c0 = (o*16+ci)*2 + kk;
    float a0 = 0.f, a1 = 0.f;
    const float* lh0 = &lh[(pp*2+0)*65];
    const float* lh1 = &lh[(pp*2+1)*65];
    const float* lwr = &lw[cc*65];
    #pragma unroll 8
    for(int kc=0; kc<64; kc++){
      float wv = lwr[kc];
      a0 = fmaf(lh0[kc], wv, a0);
      a1 = fmaf(lh1[kc], wv, a1);
    }
    float bv = bias[c0];
    float* dst = gb + (size_t)ci*2048 + kk*1024 + o*64 + pgg*8 + pp*2;
    *(float2*)dst = make_float2(a0 + bv, a1 + bv);
  }
}

// ---- slice v6: 17-col segments, lane-transposed, bias plane as scalars ----
// LDS 25.1 KB -> 6 blocks/CU. weights: 2 chunks x 1040 float2; bias: 2 x 1056 f.
__global__ void k_slice(const float* __restrict__ x, const float* __restrict__ gv,
                        float* __restrict__ outp, float* __restrict__ pacc){
  __shared__ float lds[6272];
  int xseg = blockIdx.x, hp = blockIdx.y, b = blockIdx.z;
  int tid = threadIdx.x;
  const float* gb = gv + (size_t)b*(64*16*2048);
  int y0 = (hp*63)/255;
  int y1 = min(y0+1, 63);
  float fy = hp*(63.f/255.f) - (float)y0;

  // stage + y-blend: 128 threads = {64 weight half-lines, 64 bias half-lines}
  if(tid < 128){
    int role = tid >> 6;            // 0 = weights(k=0), 1 = bias(k=1)
    int r = tid & 63;
    int half = r & 1, o = (r>>1)&15, cix = (r>>5)&1;
    int xs = min(xseg + cix, 15);
    const float* b0p = gb + (size_t)(y0*16+xs)*2048 + role*1024 + o*64;
    const float* b1p = gb + (size_t)(y1*16+xs)*2048 + role*1024 + o*64;
    int j0 = half*8;
    if(role == 0){
      float2* d = (float2*)lds + cix*1040 + o*65;
      float prev = 0.f;
      if(half){
        float a = b0p[31], c = b1p[31];
        prev = fmaf(fy, c-a, a);
      }
      #pragma unroll
      for(int j=0; j<8; ++j){
        int jj = j0 + j;
        float4 a = *(const float4*)(b0p + jj*4);
        float4 c = *(const float4*)(b1p + jj*4);
        float v0 = fmaf(fy, c.x-a.x, a.x);
        float v1 = fmaf(fy, c.y-a.y, a.y);
        float v2 = fmaf(fy, c.z-a.z, a.z);
        float v3 = fmaf(fy, c.w-a.w, a.w);
        if(j > 0 || half) d[4*jj-1] = make_float2(prev, v0);
        d[4*jj]   = make_float2(v0, v1);
        d[4*jj+1] = make_float2(v1, v2);
        d[4*jj+2] = make_float2(v2, v3);
        prev = v3;
      }
      if(half) d[63] = make_float2(prev, prev);
    } else {
      float* d = lds + 4160 + cix*1056 + o*66;
      float last = 0.f;
      #pragma unroll
      for(int j=0; j<8; ++j){
        int jj = j0 + j;
        float4 a = *(const float4*)(b0p + jj*4);
        float4 c = *(const float4*)(b1p + jj*4);
        float v0 = fmaf(fy, c.x-a.x, a.x);
        float v1 = fmaf(fy, c.y-a.y, a.y);
        float v2 = fmaf(fy, c.z-a.z, a.z);
        float v3 = fmaf(fy, c.w-a.w, a.w);
        d[4*jj]   = v0;
        d[4*jj+1] = v1;
        d[4*jj+2] = v2;
        d[4*jj+3] = v3;
        last = v3;
      }
      if(half) d[64] = last;        // z=64 tap clamps to z=63
    }
  }
  __syncthreads();

  int wv = tid>>6, lane = tid&63;
  int o = lane & 15, pl = lane >> 4;  // 16 lanes = 16 o of ONE pixel
  int lc = wv*4 + pl;                 // 0..19 (17+ invalid)
  int wq = xseg*17 + lc;
  bool act = (lc < 17) && (wq < 256);
  int wqc = min(wq, 255);

  float fx = (float)lc * (1.f/17.f);
  float cwA = 1.f - fx, cwB = fx;
  int ob65 = o*65, ob66 = o*66;
  const float2* l2w = (const float2*)lds;
  const float* lb = lds + 4160;

  float acc = 0.f, bacc = 0.f;
  for(int i=0; i<CIc; i++){
    float xv = x[((size_t)(b*CIc+i)*Hc + hp)*Wc + wqc];
    float g = fminf(fmaxf(xv, 0.f), 1.f);
    float pz = g*63.f;
    int z0 = (int)pz; float fz = pz - (float)z0;
    float wz0 = cwA*(1.f-fz), wz1 = cwA*fz;
    float vz0 = cwB*(1.f-fz), vz1 = cwB*fz;
    float2 wA = l2w[ob65 + z0];
    float2 wB = l2w[1040 + ob65 + z0];
    float bA0 = lb[ob66 + z0],        bA1 = lb[ob66 + z0 + 1];
    float bB0 = lb[1056 + ob66 + z0], bB1 = lb[1056 + ob66 + z0 + 1];
    float wsum = fmaf(wz0, wA.x, fmaf(wz1, wA.y, fmaf(vz0, wB.x, vz1*wB.y)));
    float bsum = fmaf(wz0, bA0, fmaf(wz1, bA1, fmaf(vz0, bB0, vz1*bB1)));
    acc  = fmaf(xv, wsum, acc);
    bacc += bsum;
  }
  float vout = act ? (acc + bacc*(1.f/16.f)) : 0.f;
  if(act)
    outp[((size_t)(b*COc+o)*Hc + hp)*Wc + wq] = vout;

  // deterministic stats: sum over 4 pixel-groups, then 5 waves via LDS
  float sm = vout, sq = vout*vout;
  sm += __shfl_xor(sm,16); sq += __shfl_xor(sq,16);
  sm += __shfl_xor(sm,32); sq += __shfl_xor(sq,32);
  __syncthreads();
  if(lane < 16){ lds[(wv*16+o)*2] = sm; lds[(wv*16+o)*2+1] = sq; }
  __syncthreads();
  if(tid < 32){
    int oo = tid>>1, kd = tid&1;
    float S = (((lds[(0*16+oo)*2+kd] + lds[(1*16+oo)*2+kd])
             +  (lds[(2*16+oo)*2+kd] + lds[(3*16+oo)*2+kd]))
             +   lds[(4*16+oo)*2+kd]);
    int blk = (b*256 + hp)*16 + xseg;       // P=8192
    pacc[kd*131072 + oo*8192 + blk] = S;    // CP = 16*8192
  }
}

// ---- final BN + SiLU in place on d_out ----
__global__ void k_final(float* __restrict__ out, const float* __restrict__ A,
                        const float* __restrict__ B){
  int idx = blockIdx.x*256 + threadIdx.x;
  int c = (idx>>16)&15;
  float y = fmaf(out[idx], A[c], B[c]);
  out[idx] = y / (1.f + expf(-y));
}

} // namespace

extern "C" void kernel_launch(void* const* d_in, const int* in_sizes, int n_in,
                              void* d_out, int out_size, void* d_ws, size_t ws_size,
                              hipStream_t stream){
  const float* x       = (const float*)d_in[0];
  const float* conv0_w = (const float*)d_in[1];
  const float* conv0_b = (const float*)d_in[2];
  const float* prelu0  = (const float*)d_in[3];
  const float* c1w  = (const float*)d_in[4];
  const float* c1b  = (const float*)d_in[5];
  const float* bn1g = (const float*)d_in[6];
  const float* bn1b = (const float*)d_in[7];
  const float* p1   = (const float*)d_in[8];
  const float* dww  = (const float*)d_in[9];
  const float* dwb  = (const float*)d_in[10];
  const float* bn2g = (const float*)d_in[11];
  const float* bn2b = (const float*)d_in[12];
  const float* p2   = (const float*)d_in[13];
  const float* c3w  = (const float*)d_in[14];
  const float* c3b  = (const float*)d_in[15];
  const float* bn3g = (const float*)d_in[16];
  const float* bn3b = (const float*)d_in[17];
  const float* p3   = (const float*)d_in[18];
  const float* hw   = (const float*)d_in[19];
  const float* hb   = (const float*)d_in[20];
  const float* obg  = (const float*)d_in[21];
  const float* obb  = (const float*)d_in[22];
  float* out = (float*)d_out;
  float* ws  = (float*)d_ws;

  // workspace (floats)
  float* xd    = ws;                 // 131072
  float* h     = xd + 131072;        // 524288
  float* A     = h  + 524288;        // 320
  float* B     = A  + 320;           // 320
  float* pacc  = B  + 320;           // 81920  BN1 partials
  float* paccb = pacc + 81920;       // 20480  BN2 partials
  float* paccc = paccb + 20480;      // 65536  BN3 partials
  float* t1    = paccc + 65536;      // 2621440
  float* t2    = t1 + 2621440;       // 2621440
  float* ts    = t2 + 2621440;       // 524288
  float* gv    = t1;                 // 4194304 aliases t1+t2 (dead by head)
  float* pacc2 = ts;                 // 262144 slice partials alias ts

  k_down <<<512,  256, 0, stream>>>(x, xd);
  k_conv0<<<2048, 256, 0, stream>>>(xd, conv0_w, conv0_b, prelu0, h);

  for(int i=0; i<3; i++){
    k_c1  <<<dim3(8,64,Bn), 256, 0, stream>>>(h, c1w + i*20480, c1b + i*320, t1, pacc);
    k_dw_s<<<10240, 256, 0, stream>>>(t1, dww + i*2880, dwb + i*320,
                                      bn1g+i*320, bn1b+i*320, p1+i, pacc, t2, paccb);
    k_c3f <<<dim3(256,Bn), 256, 0, stream>>>(t2, c3w + i*20480, c3b + i*64,
                                             bn2g+i*320, bn2b+i*320, p2+i, paccb, ts, paccc);
    k_addres<<<2048, 256, 0, stream>>>(ts, h, bn3g+i*64, bn3b+i*64, p3+i, paccc);
  }

  k_head_t<<<1024, 256, 0, stream>>>(h, hw, hb, gv);
  k_slice <<<dim3(16,256,Bn), 320, 0, stream>>>(x, gv, out, pacc2);
  k_fin   <<<16, 256, 0, stream>>>(pacc2, 8192, 1.f/131072.f, obg, obb, A, B);
  k_final <<<8192, 256, 0, stream>>>(out, A, B);
}

// Round 27
// 448.786 us; speedup vs baseline: 1.0011x; 1.0011x over previous
//
#include <hip/hip_runtime.h>
#include <math.h>

namespace {

constexpr int Bn=2, CIc=16, COc=16, Hc=256, Wc=256, HIDc=64, C5c=320;
constexpr int SPc = 4096;               // 64*64
constexpr float EPSc = 1e-5f;

// ---- 4x4 mean downsample: x (B,16,256,256) -> xd (B,16,64,64) ----
__global__ void k_down(const float* __restrict__ x, float* __restrict__ xd){
  int idx = blockIdx.x*blockDim.x + threadIdx.x;
  if (idx >= Bn*CIc*SPc) return;
  int q = idx & 63, p = (idx>>6)&63, c = idx>>12;
  const float* xp = x + ((size_t)c*Hc + p*4)*Wc + q*4;
  float s = 0.f;
  #pragma unroll
  for(int dy=0; dy<4; dy++)
    #pragma unroll
    for(int dx=0; dx<4; dx++) s += xp[dy*Wc+dx];
  xd[idx] = s * (1.f/16.f);
}

// ---- conv0 3x3 pad1 (16->64) + scalar PReLU ----
__global__ void k_conv0(const float* __restrict__ xd, const float* __restrict__ w,
                        const float* __restrict__ bias, const float* __restrict__ a0,
                        float* __restrict__ h){
  int idx = blockIdx.x*blockDim.x + threadIdx.x;
  if (idx >= Bn*HIDc*SPc) return;
  int q = idx&63, p=(idx>>6)&63, co=(idx>>12)&63, b=idx/(HIDc*SPc);
  float acc = bias[co];
  for(int ci=0; ci<CIc; ci++){
    const float* xp = xd + (size_t)(b*CIc+ci)*SPc;
    const float* wp = w + (co*CIc+ci)*9;
    #pragma unroll
    for(int u=0; u<3; u++){
      int pp = p+u-1; if((unsigned)pp >= 64u) continue;
      #pragma unroll
      for(int v=0; v<3; v++){
        int qq = q+v-1; if((unsigned)qq >= 64u) continue;
        acc = fmaf(xp[pp*64+qq], wp[u*3+v], acc);
      }
    }
  }
  float a = a0[0];
  h[idx] = acc >= 0.f ? acc : a*acc;
}

// ---- fused 1x1 conv 64->320 + BN1 stat partials ----
__global__ void k_c1(const float* __restrict__ h, const float* __restrict__ w,
                     const float* __restrict__ bias, float* __restrict__ t1,
                     float* __restrict__ pacc){
  __shared__ float lh[64*64];
  int og = blockIdx.x, sj = blockIdx.y, b = blockIdx.z;
  int tid = threadIdx.x;
  for(int it=0; it<4; ++it){
    int f4 = tid + it*256;               // c*16 + s4
    int c = f4>>4, s4 = f4&15;
    float4 v = *(const float4*)(h + (size_t)(b*64+c)*SPc + sj*64 + s4*4);
    *(float4*)(&lh[c*64 + s4*4]) = v;
  }
  __syncthreads();
  int osub = tid>>6, s = tid&63;
  int ob = og*40 + osub*10;
  float acc[10];
  #pragma unroll
  for(int j=0;j<10;j++) acc[j] = bias[ob+j];
  for(int c=0;c<64;c++){
    float hv = lh[c*64+s];
    #pragma unroll
    for(int j=0;j<10;j++) acc[j] = fmaf(hv, w[(ob+j)*64 + c], acc[j]);
  }
  #pragma unroll
  for(int j=0;j<10;j++){
    int o = ob+j;
    t1[(size_t)(b*320+o)*SPc + sj*64 + s] = acc[j];
    float sm = acc[j], sq = acc[j]*acc[j];
    #pragma unroll
    for(int d=1; d<64; d<<=1){ sm += __shfl_xor(sm,d); sq += __shfl_xor(sq,d); }
    if(s==0){
      pacc[o*128 + b*64 + sj]         = sm;   // P=128
      pacc[40960 + o*128 + b*64 + sj] = sq;   // CP = 320*128
    }
  }
}

// ---- finalize (out-BN only): partials -> A,B ----
__global__ void k_fin(const float* __restrict__ pacc, int P, float invN,
                      const float* __restrict__ g, const float* __restrict__ bb,
                      float* __restrict__ A, float* __restrict__ B){
  __shared__ double sh[256], sh2[256];
  int c = blockIdx.x, C = gridDim.x, tid = threadIdx.x;
  double s=0.0, s2=0.0;
  for(int p=tid; p<P; p+=256){
    s  += (double)pacc[c*P+p];
    s2 += (double)pacc[C*P + c*P + p];
  }
  sh[tid]=s; sh2[tid]=s2; __syncthreads();
  for(int off=128; off>0; off>>=1){
    if(tid<off){ sh[tid]+=sh[tid+off]; sh2[tid]+=sh2[tid+off]; }
    __syncthreads();
  }
  if(tid==0){
    float m = (float)(sh[0]*(double)invN);
    float v = (float)(sh2[0]*(double)invN) - m*m;
    float r = rsqrtf(v + EPSc);
    float gc = g[c];
    A[c] = gc*r;
    B[c] = bb[c] - m*gc*r;
  }
}

// ---- depthwise 3x3; BN1 finalized in prologue; BN2 partials out ----
__global__ void k_dw_s(const float* __restrict__ t1, const float* __restrict__ w,
                       const float* __restrict__ bias, const float* __restrict__ g1,
                       const float* __restrict__ bb1, const float* __restrict__ ap,
                       const float* __restrict__ pin, float* __restrict__ t2,
                       float* __restrict__ pout){
  int tid = threadIdx.x;
  int idx = blockIdx.x*256 + tid;
  int q = idx&63, p=(idx>>6)&63, c=(idx>>12)%C5c, b=idx/(C5c*SPc);
  __shared__ float sAB[2];
  __shared__ float ws4[4];
  {
    float v = (tid<128) ? pin[c*128 + tid] : pin[40960 + c*128 + (tid-128)];
    #pragma unroll
    for(int d=1; d<64; d<<=1) v += __shfl_xor(v, d);
    int wv = tid>>6, ln = tid&63;
    if(ln==0) ws4[wv] = v;
    __syncthreads();
    if(tid==0){
      float S = ws4[0]+ws4[1], Q = ws4[2]+ws4[3];
      float m = S*(1.f/8192.f);
      float var = Q*(1.f/8192.f) - m*m;
      float r = rsqrtf(var + EPSc);
      float gc = g1[c];
      sAB[0] = gc*r; sAB[1] = bb1[c] - m*gc*r;
    }
    __syncthreads();
  }
  float a1 = sAB[0], b1 = sAB[1], al = ap[0];
  const float* ip = t1 + (size_t)(b*C5c+c)*SPc;
  const float* wp = w + c*9;
  float acc = bias[c];
  #pragma unroll
  for(int u=0; u<3; u++){
    int pp = p+u-1; if((unsigned)pp >= 64u) continue;
    #pragma unroll
    for(int v=0; v<3; v++){
      int qq = q+v-1; if((unsigned)qq >= 64u) continue;
      float y = fmaf(ip[pp*64+qq], a1, b1);
      y = y >= 0.f ? y : al*y;
      acc = fmaf(y, wp[u*3+v], acc);
    }
  }
  t2[idx] = acc;
  float sm = acc, sq = acc*acc;
  #pragma unroll
  for(int d=1; d<64; d<<=1){ sm += __shfl_xor(sm,d); sq += __shfl_xor(sq,d); }
  __shared__ float sred[8];
  int wv = tid>>6, ln = tid&63;
  if(ln==0){ sred[wv]=sm; sred[4+wv]=sq; }
  __syncthreads();
  if(tid==0){
    float S = ((sred[0]+sred[1])+(sred[2]+sred[3]));
    float Q = ((sred[4]+sred[5])+(sred[6]+sred[7]));
    int j = blockIdx.x & 15;
    pout[c*32 + b*16 + j]         = S;   // P=32
    pout[10240 + c*32 + b*16 + j] = Q;   // CP = 320*32
  }
}

// ---- full-K 1x1 conv 320->64; BN2 finalized in prologue; BN3 partials out ----
__global__ void k_c3f(const float* __restrict__ t2, const float* __restrict__ w,
                      const float* __restrict__ bias, const float* __restrict__ g2,
                      const float* __restrict__ bb2, const float* __restrict__ ap,
                      const float* __restrict__ pin, float* __restrict__ ts,
                      float* __restrict__ pout){
  __shared__ float sA[320], sB[320];
  __shared__ float li[320*16];    // 20 KB
  int sjf = blockIdx.x, b = blockIdx.y;
  int tid = threadIdx.x;
  for(int c = tid; c < 320; c += 256){
    const float4* ps = (const float4*)(pin + c*32);
    const float4* pq = (const float4*)(pin + 10240 + c*32);
    float S=0.f, Q=0.f;
    #pragma unroll
    for(int j=0;j<8;j++){ float4 a = ps[j]; S += ((a.x+a.y)+(a.z+a.w)); }
    #pragma unroll
    for(int j=0;j<8;j++){ float4 a = pq[j]; Q += ((a.x+a.y)+(a.z+a.w)); }
    float m = S*(1.f/8192.f);
    float var = Q*(1.f/8192.f) - m*m;
    float r = rsqrtf(var + EPSc);
    float gc = g2[c];
    sA[c] = gc*r; sB[c] = bb2[c] - m*gc*r;
  }
  __syncthreads();
  float al = ap[0];
  for(int t = tid; t < 1280; t += 256){
    int c = t>>2, k4 = t&3;
    float4 v = *(const float4*)(t2 + (size_t)(b*C5c+c)*SPc + sjf*16 + k4*4);
    float a1 = sA[c], b1 = sB[c];
    float4 y;
    y.x = fmaf(v.x, a1, b1); y.x = y.x>=0.f ? y.x : al*y.x;
    y.y = fmaf(v.y, a1, b1); y.y = y.y>=0.f ? y.y : al*y.y;
    y.z = fmaf(v.z, a1, b1); y.z = y.z>=0.f ? y.z : al*y.z;
    y.w = fmaf(v.w, a1, b1); y.w = y.w>=0.f ? y.w : al*y.w;
    *(float4*)(&li[c*16 + k4*4]) = y;
  }
  __syncthreads();
  int og = tid>>4, s = tid&15;
  float acc[4];
  #pragma unroll
  for(int j=0;j<4;j++) acc[j] = bias[og*4+j];
  const float* wb = w + (size_t)(og*4)*C5c;
  for(int c=0; c<320; c++){
    float hv = li[c*16 + s];
    #pragma unroll
    for(int j=0;j<4;j++)
      acc[j] = fmaf(hv, wb[j*C5c + c], acc[j]);
  }
  #pragma unroll
  for(int j=0;j<4;j++){
    int o = og*4+j;
    ts[(size_t)(b*64+o)*SPc + sjf*16 + s] = acc[j];
    float sm = acc[j], sq = acc[j]*acc[j];
    #pragma unroll
    for(int d=1; d<16; d<<=1){ sm += __shfl_xor(sm,d); sq += __shfl_xor(sq,d); }
    if(s==0){
      pout[o*512 + b*256 + sjf]         = sm;  // P=512
      pout[32768 + o*512 + b*256 + sjf] = sq;  // CP = 64*512
    }
  }
}

// ---- BN3 (finalized in prologue, P=512) + PReLU3 + residual add into h ----
__global__ void k_addres(const float* __restrict__ ts, float* __restrict__ h,
                         const float* __restrict__ g3, const float* __restrict__ bb3,
                         const float* __restrict__ ap, const float* __restrict__ pin){
  int tid = threadIdx.x;
  int idx = blockIdx.x*256 + tid;
  int c = (idx>>12)&63;              // constant per block
  __shared__ float sAB[2];
  __shared__ float w8[8];
  {
    float S = pin[c*512 + tid] + pin[c*512 + 256 + tid];
    float Q = pin[32768 + c*512 + tid] + pin[32768 + c*512 + 256 + tid];
    #pragma unroll
    for(int d=1; d<64; d<<=1){ S += __shfl_xor(S,d); Q += __shfl_xor(Q,d); }
    int wv = tid>>6, ln = tid&63;
    if(ln==0){ w8[wv] = S; w8[4+wv] = Q; }
    __syncthreads();
    if(tid==0){
      float Sa = (w8[0]+w8[1])+(w8[2]+w8[3]);
      float Qa = (w8[4]+w8[5])+(w8[6]+w8[7]);
      float m = Sa*(1.f/8192.f);
      float var = Qa*(1.f/8192.f) - m*m;
      float r = rsqrtf(var + EPSc);
      float gc = g3[c];
      sAB[0] = gc*r; sAB[1] = bb3[c] - m*gc*r;
    }
    __syncthreads();
  }
  float y = fmaf(ts[idx], sAB[0], sAB[1]);
  float al = ap[0];
  y = y >= 0.f ? y : al*y;
  h[idx] += y;
}

// ---- head v2: 1x1 conv (64->512) -> gvol [b][q][ci][k][o][z=p] ----
__global__ void k_head_t(const float* __restrict__ h, const float* __restrict__ w,
                         const float* __restrict__ bias, float* __restrict__ gv){
  __shared__ float lh[8*65];      // [p8][kc64]
  __shared__ float lw[64*65];     // [cc64][kc64]
  int bid = blockIdx.x;           // (b*64 + q)*8 + pgg
  int pgg = bid & 7, q = (bid>>3) & 63, b = bid >> 9;
  int tid = threadIdx.x;
  for(int t = tid; t < 512; t += 256){
    int p = t >> 6, kc = t & 63;
    lh[p*65 + kc] = h[((size_t)(b*64+kc))*SPc + (pgg*8+p)*64 + q];
  }
  int cc = tid & 63, pp = tid >> 6;     // wave-uniform pp
  float* gb = gv + (size_t)b*(64*16*2048) + ((size_t)q*16)*2048;
  for(int ch = 0; ch < 8; ++ch){
    __syncthreads();
    for(int t = tid; t < 1024; t += 256){
      int rc = t >> 4, f4 = t & 15;
      int combo = ch*64 + rc;
      int ci = combo>>5, kk = (combo>>4)&1, o = combo&15;
      int c0 = (o*16+ci)*2 + kk;
      float4 v = *(const float4*)(w + (size_t)c0*64 + f4*4);
      *(float4*)(&lw[rc*65 + f4*4]) = v;
    }
    __syncthreads();
    int combo = ch*64 + cc;
    int ci = combo>>5, kk = (combo>>4)&1, o = combo&15;
    int c0 = (o*16+ci)*2 + kk;
    float a0 = 0.f, a1 = 0.f;
    const float* lh0 = &lh[(pp*2+0)*65];
    const float* lh1 = &lh[(pp*2+1)*65];
    const float* lwr = &lw[cc*65];
    #pragma unroll 8
    for(int kc=0; kc<64; kc++){
      float wv = lwr[kc];
      a0 = fmaf(lh0[kc], wv, a0);
      a1 = fmaf(lh1[kc], wv, a1);
    }
    float bv = bias[c0];
    float* dst = gb + (size_t)ci*2048 + kk*1024 + o*64 + pgg*8 + pp*2;
    *(float2*)dst = make_float2(a0 + bv, a1 + bv);
  }
}

// ---- slice v5: 17-col segments, lane-transposed (16 lanes = 16 o, 1 px) ----
__global__ void k_slice(const float* __restrict__ x, const float* __restrict__ gv,
                        float* __restrict__ outp, float* __restrict__ pacc){
  __shared__ float lds[8320];     // 4160 float2
  int xseg = blockIdx.x, hp = blockIdx.y, b = blockIdx.z;
  int tid = threadIdx.x;
  const float* gb = gv + (size_t)b*(64*16*2048);
  int y0 = (hp*63)/255;
  int y1 = min(y0+1, 63);
  float fy = hp*(63.f/255.f) - (float)y0;

  if(tid < 128){
    int half = tid & 1, o = (tid>>1)&15, k = (tid>>5)&1, cix = (tid>>6)&1;
    int xs = min(xseg + cix, 15);
    const float* b0p = gb + (size_t)(y0*16+xs)*2048 + k*1024 + o*64;
    const float* b1p = gb + (size_t)(y1*16+xs)*2048 + k*1024 + o*64;
    float2* d = (float2*)lds + cix*2080 + k*1040 + o*65;
    float prev = 0.f;
    if(half){
      float a = b0p[31], c = b1p[31];
      prev = fmaf(fy, c-a, a);
    }
    int j0 = half*8;
    #pragma unroll
    for(int j=0; j<8; ++j){
      int jj = j0 + j;
      float4 a = *(const float4*)(b0p + jj*4);
      float4 c = *(const float4*)(b1p + jj*4);
      float v0 = fmaf(fy, c.x-a.x, a.x);
      float v1 = fmaf(fy, c.y-a.y, a.y);
      float v2 = fmaf(fy, c.z-a.z, a.z);
      float v3 = fmaf(fy, c.w-a.w, a.w);
      if(j > 0 || half) d[4*jj-1] = make_float2(prev, v0);
      d[4*jj]   = make_float2(v0, v1);
      d[4*jj+1] = make_float2(v1, v2);
      d[4*jj+2] = make_float2(v2, v3);
      prev = v3;
    }
    if(half) d[63] = make_float2(prev, prev);
  }
  __syncthreads();

  int wv = tid>>6, lane = tid&63;
  int o = lane & 15, pl = lane >> 4;  // 16 lanes = 16 o of ONE pixel
  int lc = wv*4 + pl;                 // 0..19 (17+ invalid)
  int wq = xseg*17 + lc;
  bool act = (lc < 17) && (wq < 256);
  int wqc = min(wq, 255);

  float fx = (float)lc * (1.f/17.f);
  float cwA = 1.f - fx, cwB = fx;
  int obase = o*65;
  const float2* l2 = (const float2*)lds;

  float acc = 0.f, bacc = 0.f;
  for(int i=0; i<CIc; i++){
    float xv = x[((size_t)(b*CIc+i)*Hc + hp)*Wc + wqc];
    float g = fminf(fmaxf(xv, 0.f), 1.f);
    float pz = g*63.f;
    int z0 = (int)pz; float fz = pz - (float)z0;
    float wz0 = cwA*(1.f-fz), wz1 = cwA*fz;
    float vz0 = cwB*(1.f-fz), vz1 = cwB*fz;
    int aA = obase + z0, aB = 2080 + obase + z0;
    float2 wA = l2[aA],        wB = l2[aB];
    float2 bA = l2[aA + 1040], bB = l2[aB + 1040];
    float wsum = fmaf(wz0, wA.x, fmaf(wz1, wA.y, fmaf(vz0, wB.x, vz1*wB.y)));
    float bsum = fmaf(wz0, bA.x, fmaf(wz1, bA.y, fmaf(vz0, bB.x, vz1*bB.y)));
    acc  = fmaf(xv, wsum, acc);
    bacc += bsum;
  }
  float vout = act ? (acc + bacc*(1.f/16.f)) : 0.f;
  if(act)
    outp[((size_t)(b*COc+o)*Hc + hp)*Wc + wq] = vout;

  float sm = vout, sq = vout*vout;
  sm += __shfl_xor(sm,16); sq += __shfl_xor(sq,16);
  sm += __shfl_xor(sm,32); sq += __shfl_xor(sq,32);
  __syncthreads();
  if(lane < 16){ lds[(wv*16+o)*2] = sm; lds[(wv*16+o)*2+1] = sq; }
  __syncthreads();
  if(tid < 32){
    int oo = tid>>1, kd = tid&1;
    float S = (((lds[(0*16+oo)*2+kd] + lds[(1*16+oo)*2+kd])
             +  (lds[(2*16+oo)*2+kd] + lds[(3*16+oo)*2+kd]))
             +   lds[(4*16+oo)*2+kd]);
    int blk = (b*256 + hp)*16 + xseg;       // P=8192
    pacc[kd*131072 + oo*8192 + blk] = S;    // CP = 16*8192
  }
}

// ---- final BN + SiLU in place on d_out ----
__global__ void k_final(float* __restrict__ out, const float* __restrict__ A,
                        const float* __restrict__ B){
  int idx = blockIdx.x*256 + threadIdx.x;
  int c = (idx>>16)&15;
  float y = fmaf(out[idx], A[c], B[c]);
  out[idx] = y / (1.f + expf(-y));
}

} // namespace

extern "C" void kernel_launch(void* const* d_in, const int* in_sizes, int n_in,
                              void* d_out, int out_size, void* d_ws, size_t ws_size,
                              hipStream_t stream){
  const float* x       = (const float*)d_in[0];
  const float* conv0_w = (const float*)d_in[1];
  const float* conv0_b = (const float*)d_in[2];
  const float* prelu0  = (const float*)d_in[3];
  const float* c1w  = (const float*)d_in[4];
  const float* c1b  = (const float*)d_in[5];
  const float* bn1g = (const float*)d_in[6];
  const float* bn1b = (const float*)d_in[7];
  const float* p1   = (const float*)d_in[8];
  const float* dww  = (const float*)d_in[9];
  const float* dwb  = (const float*)d_in[10];
  const float* bn2g = (const float*)d_in[11];
  const float* bn2b = (const float*)d_in[12];
  const float* p2   = (const float*)d_in[13];
  const float* c3w  = (const float*)d_in[14];
  const float* c3b  = (const float*)d_in[15];
  const float* bn3g = (const float*)d_in[16];
  const float* bn3b = (const float*)d_in[17];
  const float* p3   = (const float*)d_in[18];
  const float* hw   = (const float*)d_in[19];
  const float* hb   = (const float*)d_in[20];
  const float* obg  = (const float*)d_in[21];
  const float* obb  = (const float*)d_in[22];
  float* out = (float*)d_out;
  float* ws  = (float*)d_ws;

  // workspace (floats)
  float* xd    = ws;                 // 131072
  float* h     = xd + 131072;        // 524288
  float* A     = h  + 524288;        // 320
  float* B     = A  + 320;           // 320
  float* pacc  = B  + 320;           // 81920  BN1 partials
  float* paccb = pacc + 81920;       // 20480  BN2 partials
  float* paccc = paccb + 20480;      // 65536  BN3 partials
  float* t1    = paccc + 65536;      // 2621440
  float* t2    = t1 + 2621440;       // 2621440
  float* ts    = t2 + 2621440;       // 524288
  float* gv    = t1;                 // 4194304 aliases t1+t2 (dead by head)
  float* pacc2 = ts;                 // 262144 slice partials alias ts

  k_down <<<512,  256, 0, stream>>>(x, xd);
  k_conv0<<<2048, 256, 0, stream>>>(xd, conv0_w, conv0_b, prelu0, h);

  for(int i=0; i<3; i++){
    k_c1  <<<dim3(8,64,Bn), 256, 0, stream>>>(h, c1w + i*20480, c1b + i*320, t1, pacc);
    k_dw_s<<<10240, 256, 0, stream>>>(t1, dww + i*2880, dwb + i*320,
                                      bn1g+i*320, bn1b+i*320, p1+i, pacc, t2, paccb);
    k_c3f <<<dim3(256,Bn), 256, 0, stream>>>(t2, c3w + i*20480, c3b + i*64,
                                             bn2g+i*320, bn2b+i*320, p2+i, paccb, ts, paccc);
    k_addres<<<2048, 256, 0, stream>>>(ts, h, bn3g+i*64, bn3b+i*64, p3+i, paccc);
  }

  k_head_t<<<1024, 256, 0, stream>>>(h, hw, hb, gv);
  k_slice <<<dim3(16,256,Bn), 320, 0, stream>>>(x, gv, out, pacc2);
  k_fin   <<<16, 256, 0, stream>>>(pacc2, 8192, 1.f/131072.f, obg, obb, A, B);
  k_final <<<8192, 256, 0, stream>>>(out, A, B);
}

// Round 28
// 351.584 us; speedup vs baseline: 1.2778x; 1.2765x over previous
//
#include <hip/hip_runtime.h>
#include <math.h>

namespace {

constexpr int Bn=2, CIc=16, COc=16, Hc=256, Wc=256, HIDc=64, C5c=320;
constexpr int SPc = 4096;               // 64*64
constexpr float EPSc = 1e-5f;

// ---- 4x4 mean downsample: x (B,16,256,256) -> xd (B,16,64,64) ----
__global__ void k_down(const float* __restrict__ x, float* __restrict__ xd){
  int idx = blockIdx.x*blockDim.x + threadIdx.x;
  if (idx >= Bn*CIc*SPc) return;
  int q = idx & 63, p = (idx>>6)&63, c = idx>>12;
  const float* xp = x + ((size_t)c*Hc + p*4)*Wc + q*4;
  float s = 0.f;
  #pragma unroll
  for(int dy=0; dy<4; dy++)
    #pragma unroll
    for(int dx=0; dx<4; dx++) s += xp[dy*Wc+dx];
  xd[idx] = s * (1.f/16.f);
}

// ---- conv0 3x3 pad1 (16->64) + scalar PReLU ----
__global__ void k_conv0(const float* __restrict__ xd, const float* __restrict__ w,
                        const float* __restrict__ bias, const float* __restrict__ a0,
                        float* __restrict__ h){
  int idx = blockIdx.x*blockDim.x + threadIdx.x;
  if (idx >= Bn*HIDc*SPc) return;
  int q = idx&63, p=(idx>>6)&63, co=(idx>>12)&63, b=idx/(HIDc*SPc);
  float acc = bias[co];
  for(int ci=0; ci<CIc; ci++){
    const float* xp = xd + (size_t)(b*CIc+ci)*SPc;
    const float* wp = w + (co*CIc+ci)*9;
    #pragma unroll
    for(int u=0; u<3; u++){
      int pp = p+u-1; if((unsigned)pp >= 64u) continue;
      #pragma unroll
      for(int v=0; v<3; v++){
        int qq = q+v-1; if((unsigned)qq >= 64u) continue;
        acc = fmaf(xp[pp*64+qq], wp[u*3+v], acc);
      }
    }
  }
  float a = a0[0];
  h[idx] = acc >= 0.f ? acc : a*acc;
}

// ---- fused 1x1 conv 64->320 + BN1 stat partials; 4s x 5o register tile ----
// grid (4 og, 64 sj, Bn), 256 thr = 16 oj x 16 sq. Block: 80 outs x 64 px.
// Issue density: 4 LDS + 5 scalar-w per 20 FMA (was 1 LDS + 10 w per 10 FMA).
__global__ void k_c1(const float* __restrict__ h, const float* __restrict__ w,
                     const float* __restrict__ bias, float* __restrict__ t1,
                     float* __restrict__ pacc){
  __shared__ float lh[64*64];
  int og = blockIdx.x, sj = blockIdx.y, b = blockIdx.z;
  int tid = threadIdx.x;
  for(int it=0; it<4; ++it){
    int f4 = tid + it*256;               // c*16 + s4
    int c = f4>>4, s4 = f4&15;
    float4 v = *(const float4*)(h + (size_t)(b*64+c)*SPc + sj*64 + s4*4);
    *(float4*)(&lh[c*64 + s4*4]) = v;
  }
  __syncthreads();
  int sq = tid & 15, oj = tid >> 4;
  int ob = og*80 + oj*5;
  float acc[4][5];
  #pragma unroll
  for(int k=0;k<4;k++)
    #pragma unroll
    for(int j=0;j<5;j++) acc[k][j] = 0.f;
  const float* lhs = lh + sq*4;
  for(int c=0;c<64;c++){
    float h0 = lhs[c*64+0];
    float h1 = lhs[c*64+1];
    float h2 = lhs[c*64+2];
    float h3 = lhs[c*64+3];
    #pragma unroll
    for(int j=0;j<5;j++){
      float wv = w[(ob+j)*64 + c];
      acc[0][j] = fmaf(h0, wv, acc[0][j]);
      acc[1][j] = fmaf(h1, wv, acc[1][j]);
      acc[2][j] = fmaf(h2, wv, acc[2][j]);
      acc[3][j] = fmaf(h3, wv, acc[3][j]);
    }
  }
  #pragma unroll
  for(int j=0;j<5;j++){
    int o = ob + j;
    float bv = bias[o];
    float4 v4 = make_float4(acc[0][j]+bv, acc[1][j]+bv, acc[2][j]+bv, acc[3][j]+bv);
    *(float4*)(t1 + (size_t)(b*320+o)*SPc + sj*64 + sq*4) = v4;
    float sm  = (v4.x+v4.y)+(v4.z+v4.w);
    float sq2 = (v4.x*v4.x + v4.y*v4.y) + (v4.z*v4.z + v4.w*v4.w);
    sm += __shfl_xor(sm,1); sq2 += __shfl_xor(sq2,1);
    sm += __shfl_xor(sm,2); sq2 += __shfl_xor(sq2,2);
    sm += __shfl_xor(sm,4); sq2 += __shfl_xor(sq2,4);
    sm += __shfl_xor(sm,8); sq2 += __shfl_xor(sq2,8);
    if(sq==0){
      pacc[o*128 + b*64 + sj]         = sm;   // P=128
      pacc[40960 + o*128 + b*64 + sj] = sq2;  // CP = 320*128
    }
  }
}

// ---- finalize (out-BN only): partials -> A,B ----
__global__ void k_fin(const float* __restrict__ pacc, int P, float invN,
                      const float* __restrict__ g, const float* __restrict__ bb,
                      float* __restrict__ A, float* __restrict__ B){
  __shared__ double sh[256], sh2[256];
  int c = blockIdx.x, C = gridDim.x, tid = threadIdx.x;
  double s=0.0, s2=0.0;
  for(int p=tid; p<P; p+=256){
    s  += (double)pacc[c*P+p];
    s2 += (double)pacc[C*P + c*P + p];
  }
  sh[tid]=s; sh2[tid]=s2; __syncthreads();
  for(int off=128; off>0; off>>=1){
    if(tid<off){ sh[tid]+=sh[tid+off]; sh2[tid]+=sh2[tid+off]; }
    __syncthreads();
  }
  if(tid==0){
    float m = (float)(sh[0]*(double)invN);
    float v = (float)(sh2[0]*(double)invN) - m*m;
    float r = rsqrtf(v + EPSc);
    float gc = g[c];
    A[c] = gc*r;
    B[c] = bb[c] - m*gc*r;
  }
}

// ---- depthwise 3x3; BN1 finalized in prologue; BN2 partials out ----
__global__ void k_dw_s(const float* __restrict__ t1, const float* __restrict__ w,
                       const float* __restrict__ bias, const float* __restrict__ g1,
                       const float* __restrict__ bb1, const float* __restrict__ ap,
                       const float* __restrict__ pin, float* __restrict__ t2,
                       float* __restrict__ pout){
  int tid = threadIdx.x;
  int idx = blockIdx.x*256 + tid;
  int q = idx&63, p=(idx>>6)&63, c=(idx>>12)%C5c, b=idx/(C5c*SPc);
  __shared__ float sAB[2];
  __shared__ float ws4[4];
  {
    float v = (tid<128) ? pin[c*128 + tid] : pin[40960 + c*128 + (tid-128)];
    #pragma unroll
    for(int d=1; d<64; d<<=1) v += __shfl_xor(v, d);
    int wv = tid>>6, ln = tid&63;
    if(ln==0) ws4[wv] = v;
    __syncthreads();
    if(tid==0){
      float S = ws4[0]+ws4[1], Q = ws4[2]+ws4[3];
      float m = S*(1.f/8192.f);
      float var = Q*(1.f/8192.f) - m*m;
      float r = rsqrtf(var + EPSc);
      float gc = g1[c];
      sAB[0] = gc*r; sAB[1] = bb1[c] - m*gc*r;
    }
    __syncthreads();
  }
  float a1 = sAB[0], b1 = sAB[1], al = ap[0];
  const float* ip = t1 + (size_t)(b*C5c+c)*SPc;
  const float* wp = w + c*9;
  float acc = bias[c];
  #pragma unroll
  for(int u=0; u<3; u++){
    int pp = p+u-1; if((unsigned)pp >= 64u) continue;
    #pragma unroll
    for(int v=0; v<3; v++){
      int qq = q+v-1; if((unsigned)qq >= 64u) continue;
      float y = fmaf(ip[pp*64+qq], a1, b1);
      y = y >= 0.f ? y : al*y;
      acc = fmaf(y, wp[u*3+v], acc);
    }
  }
  t2[idx] = acc;
  float sm = acc, sq = acc*acc;
  #pragma unroll
  for(int d=1; d<64; d<<=1){ sm += __shfl_xor(sm,d); sq += __shfl_xor(sq,d); }
  __shared__ float sred[8];
  int wv = tid>>6, ln = tid&63;
  if(ln==0){ sred[wv]=sm; sred[4+wv]=sq; }
  __syncthreads();
  if(tid==0){
    float S = ((sred[0]+sred[1])+(sred[2]+sred[3]));
    float Q = ((sred[4]+sred[5])+(sred[6]+sred[7]));
    int j = blockIdx.x & 15;
    pout[c*32 + b*16 + j]         = S;   // P=32
    pout[10240 + c*32 + b*16 + j] = Q;   // CP = 320*32
  }
}

// ---- full-K 1x1 conv 320->64; BN2 finalized in prologue; BN3 partials out ----
__global__ void k_c3f(const float* __restrict__ t2, const float* __restrict__ w,
                      const float* __restrict__ bias, const float* __restrict__ g2,
                      const float* __restrict__ bb2, const float* __restrict__ ap,
                      const float* __restrict__ pin, float* __restrict__ ts,
                      float* __restrict__ pout){
  __shared__ float sA[320], sB[320];
  __shared__ float li[320*16];    // 20 KB
  int sjf = blockIdx.x, b = blockIdx.y;
  int tid = threadIdx.x;
  for(int c = tid; c < 320; c += 256){
    const float4* ps = (const float4*)(pin + c*32);
    const float4* pq = (const float4*)(pin + 10240 + c*32);
    float S=0.f, Q=0.f;
    #pragma unroll
    for(int j=0;j<8;j++){ float4 a = ps[j]; S += ((a.x+a.y)+(a.z+a.w)); }
    #pragma unroll
    for(int j=0;j<8;j++){ float4 a = pq[j]; Q += ((a.x+a.y)+(a.z+a.w)); }
    float m = S*(1.f/8192.f);
    float var = Q*(1.f/8192.f) - m*m;
    float r = rsqrtf(var + EPSc);
    float gc = g2[c];
    sA[c] = gc*r; sB[c] = bb2[c] - m*gc*r;
  }
  __syncthreads();
  float al = ap[0];
  for(int t = tid; t < 1280; t += 256){
    int c = t>>2, k4 = t&3;
    float4 v = *(const float4*)(t2 + (size_t)(b*C5c+c)*SPc + sjf*16 + k4*4);
    float a1 = sA[c], b1 = sB[c];
    float4 y;
    y.x = fmaf(v.x, a1, b1); y.x = y.x>=0.f ? y.x : al*y.x;
    y.y = fmaf(v.y, a1, b1); y.y = y.y>=0.f ? y.y : al*y.y;
    y.z = fmaf(v.z, a1, b1); y.z = y.z>=0.f ? y.z : al*y.z;
    y.w = fmaf(v.w, a1, b1); y.w = y.w>=0.f ? y.w : al*y.w;
    *(float4*)(&li[c*16 + k4*4]) = y;
  }
  __syncthreads();
  int og = tid>>4, s = tid&15;
  float acc[4];
  #pragma unroll
  for(int j=0;j<4;j++) acc[j] = bias[og*4+j];
  const float* wb = w + (size_t)(og*4)*C5c;
  for(int c=0; c<320; c++){
    float hv = li[c*16 + s];
    #pragma unroll
    for(int j=0;j<4;j++)
      acc[j] = fmaf(hv, wb[j*C5c + c], acc[j]);
  }
  #pragma unroll
  for(int j=0;j<4;j++){
    int o = og*4+j;
    ts[(size_t)(b*64+o)*SPc + sjf*16 + s] = acc[j];
    float sm = acc[j], sq = acc[j]*acc[j];
    #pragma unroll
    for(int d=1; d<16; d<<=1){ sm += __shfl_xor(sm,d); sq += __shfl_xor(sq,d); }
    if(s==0){
      pout[o*512 + b*256 + sjf]         = sm;  // P=512
      pout[32768 + o*512 + b*256 + sjf] = sq;  // CP = 64*512
    }
  }
}

// ---- BN3 (finalized in prologue, P=512) + PReLU3 + residual add into h ----
__global__ void k_addres(const float* __restrict__ ts, float* __restrict__ h,
                         const float* __restrict__ g3, const float* __restrict__ bb3,
                         const float* __restrict__ ap, const float* __restrict__ pin){
  int tid = threadIdx.x;
  int idx = blockIdx.x*256 + tid;
  int c = (idx>>12)&63;              // constant per block
  __shared__ float sAB[2];
  __shared__ float w8[8];
  {
    float S = pin[c*512 + tid] + pin[c*512 + 256 + tid];
    float Q = pin[32768 + c*512 + tid] + pin[32768 + c*512 + 256 + tid];
    #pragma unroll
    for(int d=1; d<64; d<<=1){ S += __shfl_xor(S,d); Q += __shfl_xor(Q,d); }
    int wv = tid>>6, ln = tid&63;
    if(ln==0){ w8[wv] = S; w8[4+wv] = Q; }
    __syncthreads();
    if(tid==0){
      float Sa = (w8[0]+w8[1])+(w8[2]+w8[3]);
      float Qa = (w8[4]+w8[5])+(w8[6]+w8[7]);
      float m = Sa*(1.f/8192.f);
      float var = Qa*(1.f/8192.f) - m*m;
      float r = rsqrtf(var + EPSc);
      float gc = g3[c];
      sAB[0] = gc*r; sAB[1] = bb3[c] - m*gc*r;
    }
    __syncthreads();
  }
  float y = fmaf(ts[idx], sAB[0], sAB[1]);
  float al = ap[0];
  y = y >= 0.f ? y : al*y;
  h[idx] += y;
}

// ---- head v2: 1x1 conv (64->512) -> gvol [b][q][ci][k][o][z=p] ----
__global__ void k_head_t(const float* __restrict__ h, const float* __restrict__ w,
                         const float* __restrict__ bias, float* __restrict__ gv){
  __shared__ float lh[8*65];      // [p8][kc64]
  __shared__ float lw[64*65];     // [cc64][kc64]
  int bid = blockIdx.x;           // (b*64 + q)*8 + pgg
  int pgg = bid & 7, q = (bid>>3) & 63, b = bid >> 9;
  int tid = threadIdx.x;
  for(int t = tid; t < 512; t += 256){
    int p = t >> 6, kc = t & 63;
    lh[p*65 + kc] = h[((size_t)(b*64+kc))*SPc + (pgg*8+p)*64 + q];
  }
  int cc = tid & 63, pp = tid >> 6;     // wave-uniform pp
  float* gb = gv + (size_t)b*(64*16*2048) + ((size_t)q*16)*2048;
  for(int ch = 0; ch < 8; ++ch){
    __syncthreads();
    for(int t = tid; t < 1024; t += 256){
      int rc = t >> 4, f4 = t & 15;
      int combo = ch*64 + rc;
      int ci = combo>>5, kk = (combo>>4)&1, o = combo&15;
      int c0 = (o*16+ci)*2 + kk;
      float4 v = *(const float4*)(w + (size_t)c0*64 + f4*4);
      *(float4*)(&lw[rc*65 + f4*4]) = v;
    }
    __syncthreads();
    int combo = ch*64 + cc;
    int ci = combo>>5, kk = (combo>>4)&1, o = combo&15;
    int c0 = (o*16+ci)*2 + kk;
    float a0 = 0.f, a1 = 0.f;
    const float* lh0 = &lh[(pp*2+0)*65];
    const float* lh1 = &lh[(pp*2+1)*65];
    const float* lwr = &lw[cc*65];
    #pragma unroll 8
    for(int kc=0; kc<64; kc++){
      float wv = lwr[kc];
      a0 = fmaf(lh0[kc], wv, a0);
      a1 = fmaf(lh1[kc], wv, a1);
    }
    float bv = bias[c0];
    float* dst = gb + (size_t)ci*2048 + kk*1024 + o*64 + pgg*8 + pp*2;
    *(float2*)dst = make_float2(a0 + bv, a1 + bv);
  }
}

// ---- slice v5: 17-col segments, lane-transposed (16 lanes = 16 o, 1 px) ----
__global__ void k_slice(const float* __restrict__ x, const float* __restrict__ gv,
                        float* __restrict__ outp, float* __restrict__ pacc){
  __shared__ float lds[8320];     // 4160 float2
  int xseg = blockIdx.x, hp = blockIdx.y, b = blockIdx.z;
  int tid = threadIdx.x;
  const float* gb = gv + (size_t)b*(64*16*2048);
  int y0 = (hp*63)/255;
  int y1 = min(y0+1, 63);
  float fy = hp*(63.f/255.f) - (float)y0;

  if(tid < 128){
    int half = tid & 1, o = (tid>>1)&15, k = (tid>>5)&1, cix = (tid>>6)&1;
    int xs = min(xseg + cix, 15);
    const float* b0p = gb + (size_t)(y0*16+xs)*2048 + k*1024 + o*64;
    const float* b1p = gb + (size_t)(y1*16+xs)*2048 + k*1024 + o*64;
    float2* d = (float2*)lds + cix*2080 + k*1040 + o*65;
    float prev = 0.f;
    if(half){
      float a = b0p[31], c = b1p[31];
      prev = fmaf(fy, c-a, a);
    }
    int j0 = half*8;
    #pragma unroll
    for(int j=0; j<8; ++j){
      int jj = j0 + j;
      float4 a = *(const float4*)(b0p + jj*4);
      float4 c = *(const float4*)(b1p + jj*4);
      float v0 = fmaf(fy, c.x-a.x, a.x);
      float v1 = fmaf(fy, c.y-a.y, a.y);
      float v2 = fmaf(fy, c.z-a.z, a.z);
      float v3 = fmaf(fy, c.w-a.w, a.w);
      if(j > 0 || half) d[4*jj-1] = make_float2(prev, v0);
      d[4*jj]   = make_float2(v0, v1);
      d[4*jj+1] = make_float2(v1, v2);
      d[4*jj+2] = make_float2(v2, v3);
      prev = v3;
    }
    if(half) d[63] = make_float2(prev, prev);
  }
  __syncthreads();

  int wv = tid>>6, lane = tid&63;
  int o = lane & 15, pl = lane >> 4;  // 16 lanes = 16 o of ONE pixel
  int lc = wv*4 + pl;                 // 0..19 (17+ invalid)
  int wq = xseg*17 + lc;
  bool act = (lc < 17) && (wq < 256);
  int wqc = min(wq, 255);

  float fx = (float)lc * (1.f/17.f);
  float cwA = 1.f - fx, cwB = fx;
  int obase = o*65;
  const float2* l2 = (const float2*)lds;

  float acc = 0.f, bacc = 0.f;
  for(int i=0; i<CIc; i++){
    float xv = x[((size_t)(b*CIc+i)*Hc + hp)*Wc + wqc];
    float g = fminf(fmaxf(xv, 0.f), 1.f);
    float pz = g*63.f;
    int z0 = (int)pz; float fz = pz - (float)z0;
    float wz0 = cwA*(1.f-fz), wz1 = cwA*fz;
    float vz0 = cwB*(1.f-fz), vz1 = cwB*fz;
    int aA = obase + z0, aB = 2080 + obase + z0;
    float2 wA = l2[aA],        wB = l2[aB];
    float2 bA = l2[aA + 1040], bB = l2[aB + 1040];
    float wsum = fmaf(wz0, wA.x, fmaf(wz1, wA.y, fmaf(vz0, wB.x, vz1*wB.y)));
    float bsum = fmaf(wz0, bA.x, fmaf(wz1, bA.y, fmaf(vz0, bB.x, vz1*bB.y)));
    acc  = fmaf(xv, wsum, acc);
    bacc += bsum;
  }
  float vout = act ? (acc + bacc*(1.f/16.f)) : 0.f;
  if(act)
    outp[((size_t)(b*COc+o)*Hc + hp)*Wc + wq] = vout;

  float sm = vout, sq = vout*vout;
  sm += __shfl_xor(sm,16); sq += __shfl_xor(sq,16);
  sm += __shfl_xor(sm,32); sq += __shfl_xor(sq,32);
  __syncthreads();
  if(lane < 16){ lds[(wv*16+o)*2] = sm; lds[(wv*16+o)*2+1] = sq; }
  __syncthreads();
  if(tid < 32){
    int oo = tid>>1, kd = tid&1;
    float S = (((lds[(0*16+oo)*2+kd] + lds[(1*16+oo)*2+kd])
             +  (lds[(2*16+oo)*2+kd] + lds[(3*16+oo)*2+kd]))
             +   lds[(4*16+oo)*2+kd]);
    int blk = (b*256 + hp)*16 + xseg;       // P=8192
    pacc[kd*131072 + oo*8192 + blk] = S;    // CP = 16*8192
  }
}

// ---- final BN + SiLU in place on d_out ----
__global__ void k_final(float* __restrict__ out, const float* __restrict__ A,
                        const float* __restrict__ B){
  int idx = blockIdx.x*256 + threadIdx.x;
  int c = (idx>>16)&15;
  float y = fmaf(out[idx], A[c], B[c]);
  out[idx] = y / (1.f + expf(-y));
}

} // namespace

extern "C" void kernel_launch(void* const* d_in, const int* in_sizes, int n_in,
                              void* d_out, int out_size, void* d_ws, size_t ws_size,
                              hipStream_t stream){
  const float* x       = (const float*)d_in[0];
  const float* conv0_w = (const float*)d_in[1];
  const float* conv0_b = (const float*)d_in[2];
  const float* prelu0  = (const float*)d_in[3];
  const float* c1w  = (const float*)d_in[4];
  const float* c1b  = (const float*)d_in[5];
  const float* bn1g = (const float*)d_in[6];
  const float* bn1b = (const float*)d_in[7];
  const float* p1   = (const float*)d_in[8];
  const float* dww  = (const float*)d_in[9];
  const float* dwb  = (const float*)d_in[10];
  const float* bn2g = (const float*)d_in[11];
  const float* bn2b = (const float*)d_in[12];
  const float* p2   = (const float*)d_in[13];
  const float* c3w  = (const float*)d_in[14];
  const float* c3b  = (const float*)d_in[15];
  const float* bn3g = (const float*)d_in[16];
  const float* bn3b = (const float*)d_in[17];
  const float* p3   = (const float*)d_in[18];
  const float* hw   = (const float*)d_in[19];
  const float* hb   = (const float*)d_in[20];
  const float* obg  = (const float*)d_in[21];
  const float* obb  = (const float*)d_in[22];
  float* out = (float*)d_out;
  float* ws  = (float*)d_ws;

  // workspace (floats)
  float* xd    = ws;                 // 131072
  float* h     = xd + 131072;        // 524288
  float* A     = h  + 524288;        // 320
  float* B     = A  + 320;           // 320
  float* pacc  = B  + 320;           // 81920  BN1 partials
  float* paccb = pacc + 81920;       // 20480  BN2 partials
  float* paccc = paccb + 20480;      // 65536  BN3 partials
  float* t1    = paccc + 65536;      // 2621440
  float* t2    = t1 + 2621440;       // 2621440
  float* ts    = t2 + 2621440;       // 524288
  float* gv    = t1;                 // 4194304 aliases t1+t2 (dead by head)
  float* pacc2 = ts;                 // 262144 slice partials alias ts

  k_down <<<512,  256, 0, stream>>>(x, xd);
  k_conv0<<<2048, 256, 0, stream>>>(xd, conv0_w, conv0_b, prelu0, h);

  for(int i=0; i<3; i++){
    k_c1  <<<dim3(4,64,Bn), 256, 0, stream>>>(h, c1w + i*20480, c1b + i*320, t1, pacc);
    k_dw_s<<<10240, 256, 0, stream>>>(t1, dww + i*2880, dwb + i*320,
                                      bn1g+i*320, bn1b+i*320, p1+i, pacc, t2, paccb);
    k_c3f <<<dim3(256,Bn), 256, 0, stream>>>(t2, c3w + i*20480, c3b + i*64,
                                             bn2g+i*320, bn2b+i*320, p2+i, paccb, ts, paccc);
    k_addres<<<2048, 256, 0, stream>>>(ts, h, bn3g+i*64, bn3b+i*64, p3+i, paccc);
  }

  k_head_t<<<1024, 256, 0, stream>>>(h, hw, hb, gv);
  k_slice <<<dim3(16,256,Bn), 320, 0, stream>>>(x, gv, out, pacc2);
  k_fin   <<<16, 256, 0, stream>>>(pacc2, 8192, 1.f/131072.f, obg, obb, A, B);
  k_final <<<8192, 256, 0, stream>>>(out, A, B);
}

// Round 29
// 319.575 us; speedup vs baseline: 1.4058x; 1.1002x over previous
//
#include <hip/hip_runtime.h>
#include <math.h>

namespace {

constexpr int Bn=2, CIc=16, COc=16, Hc=256, Wc=256, HIDc=64, C5c=320;
constexpr int SPc = 4096;               // 64*64
constexpr float EPSc = 1e-5f;

// ---- 4x4 mean downsample: x (B,16,256,256) -> xd (B,16,64,64) ----
__global__ void k_down(const float* __restrict__ x, float* __restrict__ xd){
  int idx = blockIdx.x*blockDim.x + threadIdx.x;
  if (idx >= Bn*CIc*SPc) return;
  int q = idx & 63, p = (idx>>6)&63, c = idx>>12;
  const float* xp = x + ((size_t)c*Hc + p*4)*Wc + q*4;
  float s = 0.f;
  #pragma unroll
  for(int dy=0; dy<4; dy++)
    #pragma unroll
    for(int dx=0; dx<4; dx++) s += xp[dy*Wc+dx];
  xd[idx] = s * (1.f/16.f);
}

// ---- conv0 3x3 pad1 (16->64) + scalar PReLU ----
__global__ void k_conv0(const float* __restrict__ xd, const float* __restrict__ w,
                        const float* __restrict__ bias, const float* __restrict__ a0,
                        float* __restrict__ h){
  int idx = blockIdx.x*blockDim.x + threadIdx.x;
  if (idx >= Bn*HIDc*SPc) return;
  int q = idx&63, p=(idx>>6)&63, co=(idx>>12)&63, b=idx/(HIDc*SPc);
  float acc = bias[co];
  for(int ci=0; ci<CIc; ci++){
    const float* xp = xd + (size_t)(b*CIc+ci)*SPc;
    const float* wp = w + (co*CIc+ci)*9;
    #pragma unroll
    for(int u=0; u<3; u++){
      int pp = p+u-1; if((unsigned)pp >= 64u) continue;
      #pragma unroll
      for(int v=0; v<3; v++){
        int qq = q+v-1; if((unsigned)qq >= 64u) continue;
        acc = fmaf(xp[pp*64+qq], wp[u*3+v], acc);
      }
    }
  }
  float a = a0[0];
  h[idx] = acc >= 0.f ? acc : a*acc;
}

// ---- fused 1x1 conv 64->320 + BN1 stat partials; 4s x 5o register tile ----
__global__ void k_c1(const float* __restrict__ h, const float* __restrict__ w,
                     const float* __restrict__ bias, float* __restrict__ t1,
                     float* __restrict__ pacc){
  __shared__ float lh[64*64];
  int og = blockIdx.x, sj = blockIdx.y, b = blockIdx.z;
  int tid = threadIdx.x;
  for(int it=0; it<4; ++it){
    int f4 = tid + it*256;               // c*16 + s4
    int c = f4>>4, s4 = f4&15;
    float4 v = *(const float4*)(h + (size_t)(b*64+c)*SPc + sj*64 + s4*4);
    *(float4*)(&lh[c*64 + s4*4]) = v;
  }
  __syncthreads();
  int sq = tid & 15, oj = tid >> 4;
  int ob = og*80 + oj*5;
  float acc[4][5];
  #pragma unroll
  for(int k=0;k<4;k++)
    #pragma unroll
    for(int j=0;j<5;j++) acc[k][j] = 0.f;
  const float* lhs = lh + sq*4;
  for(int c=0;c<64;c++){
    float h0 = lhs[c*64+0];
    float h1 = lhs[c*64+1];
    float h2 = lhs[c*64+2];
    float h3 = lhs[c*64+3];
    #pragma unroll
    for(int j=0;j<5;j++){
      float wv = w[(ob+j)*64 + c];
      acc[0][j] = fmaf(h0, wv, acc[0][j]);
      acc[1][j] = fmaf(h1, wv, acc[1][j]);
      acc[2][j] = fmaf(h2, wv, acc[2][j]);
      acc[3][j] = fmaf(h3, wv, acc[3][j]);
    }
  }
  #pragma unroll
  for(int j=0;j<5;j++){
    int o = ob + j;
    float bv = bias[o];
    float4 v4 = make_float4(acc[0][j]+bv, acc[1][j]+bv, acc[2][j]+bv, acc[3][j]+bv);
    *(float4*)(t1 + (size_t)(b*320+o)*SPc + sj*64 + sq*4) = v4;
    float sm  = (v4.x+v4.y)+(v4.z+v4.w);
    float sq2 = (v4.x*v4.x + v4.y*v4.y) + (v4.z*v4.z + v4.w*v4.w);
    sm += __shfl_xor(sm,1); sq2 += __shfl_xor(sq2,1);
    sm += __shfl_xor(sm,2); sq2 += __shfl_xor(sq2,2);
    sm += __shfl_xor(sm,4); sq2 += __shfl_xor(sq2,4);
    sm += __shfl_xor(sm,8); sq2 += __shfl_xor(sq2,8);
    if(sq==0){
      pacc[o*128 + b*64 + sj]         = sm;   // P=128
      pacc[40960 + o*128 + b*64 + sj] = sq2;  // CP = 320*128
    }
  }
}

// ---- finalize (out-BN only): partials -> A,B ----
__global__ void k_fin(const float* __restrict__ pacc, int P, float invN,
                      const float* __restrict__ g, const float* __restrict__ bb,
                      float* __restrict__ A, float* __restrict__ B){
  __shared__ double sh[256], sh2[256];
  int c = blockIdx.x, C = gridDim.x, tid = threadIdx.x;
  double s=0.0, s2=0.0;
  for(int p=tid; p<P; p+=256){
    s  += (double)pacc[c*P+p];
    s2 += (double)pacc[C*P + c*P + p];
  }
  sh[tid]=s; sh2[tid]=s2; __syncthreads();
  for(int off=128; off>0; off>>=1){
    if(tid<off){ sh[tid]+=sh[tid+off]; sh2[tid]+=sh2[tid+off]; }
    __syncthreads();
  }
  if(tid==0){
    float m = (float)(sh[0]*(double)invN);
    float v = (float)(sh2[0]*(double)invN) - m*m;
    float r = rsqrtf(v + EPSc);
    float gc = g[c];
    A[c] = gc*r;
    B[c] = bb[c] - m*gc*r;
  }
}

// ---- depthwise 3x3; BN1 finalized in prologue; BN2 partials out ----
__global__ void k_dw_s(const float* __restrict__ t1, const float* __restrict__ w,
                       const float* __restrict__ bias, const float* __restrict__ g1,
                       const float* __restrict__ bb1, const float* __restrict__ ap,
                       const float* __restrict__ pin, float* __restrict__ t2,
                       float* __restrict__ pout){
  int tid = threadIdx.x;
  int idx = blockIdx.x*256 + tid;
  int q = idx&63, p=(idx>>6)&63, c=(idx>>12)%C5c, b=idx/(C5c*SPc);
  __shared__ float sAB[2];
  __shared__ float ws4[4];
  {
    float v = (tid<128) ? pin[c*128 + tid] : pin[40960 + c*128 + (tid-128)];
    #pragma unroll
    for(int d=1; d<64; d<<=1) v += __shfl_xor(v, d);
    int wv = tid>>6, ln = tid&63;
    if(ln==0) ws4[wv] = v;
    __syncthreads();
    if(tid==0){
      float S = ws4[0]+ws4[1], Q = ws4[2]+ws4[3];
      float m = S*(1.f/8192.f);
      float var = Q*(1.f/8192.f) - m*m;
      float r = rsqrtf(var + EPSc);
      float gc = g1[c];
      sAB[0] = gc*r; sAB[1] = bb1[c] - m*gc*r;
    }
    __syncthreads();
  }
  float a1 = sAB[0], b1 = sAB[1], al = ap[0];
  const float* ip = t1 + (size_t)(b*C5c+c)*SPc;
  const float* wp = w + c*9;
  float acc = bias[c];
  #pragma unroll
  for(int u=0; u<3; u++){
    int pp = p+u-1; if((unsigned)pp >= 64u) continue;
    #pragma unroll
    for(int v=0; v<3; v++){
      int qq = q+v-1; if((unsigned)qq >= 64u) continue;
      float y = fmaf(ip[pp*64+qq], a1, b1);
      y = y >= 0.f ? y : al*y;
      acc = fmaf(y, wp[u*3+v], acc);
    }
  }
  t2[idx] = acc;
  float sm = acc, sq = acc*acc;
  #pragma unroll
  for(int d=1; d<64; d<<=1){ sm += __shfl_xor(sm,d); sq += __shfl_xor(sq,d); }
  __shared__ float sred[8];
  int wv = tid>>6, ln = tid&63;
  if(ln==0){ sred[wv]=sm; sred[4+wv]=sq; }
  __syncthreads();
  if(tid==0){
    float S = ((sred[0]+sred[1])+(sred[2]+sred[3]));
    float Q = ((sred[4]+sred[5])+(sred[6]+sred[7]));
    int j = blockIdx.x & 15;
    pout[c*32 + b*16 + j]         = S;   // P=32
    pout[10240 + c*32 + b*16 + j] = Q;   // CP = 320*32
  }
}

// ---- full-K 1x1 conv 320->64 v2: 32 px/block, 2px x 4o register tile ----
// grid (128 sjf, Bn), 256 thr = 16 oj x 16 sq. BN2 in prologue; BN3 partials.
__global__ void k_c3f(const float* __restrict__ t2, const float* __restrict__ w,
                      const float* __restrict__ bias, const float* __restrict__ g2,
                      const float* __restrict__ bb2, const float* __restrict__ ap,
                      const float* __restrict__ pin, float* __restrict__ ts,
                      float* __restrict__ pout){
  __shared__ float sA[320], sB[320];
  __shared__ float li[320*32];    // 40 KB
  int sjf = blockIdx.x, b = blockIdx.y;
  int tid = threadIdx.x;
  for(int c = tid; c < 320; c += 256){
    const float4* ps = (const float4*)(pin + c*32);
    const float4* pq = (const float4*)(pin + 10240 + c*32);
    float S=0.f, Q=0.f;
    #pragma unroll
    for(int j=0;j<8;j++){ float4 a = ps[j]; S += ((a.x+a.y)+(a.z+a.w)); }
    #pragma unroll
    for(int j=0;j<8;j++){ float4 a = pq[j]; Q += ((a.x+a.y)+(a.z+a.w)); }
    float m = S*(1.f/8192.f);
    float var = Q*(1.f/8192.f) - m*m;
    float r = rsqrtf(var + EPSc);
    float gc = g2[c];
    sA[c] = gc*r; sB[c] = bb2[c] - m*gc*r;
  }
  __syncthreads();
  float al = ap[0];
  for(int t = tid; t < 2560; t += 256){
    int c = t>>3, f8 = t&7;
    float4 v = *(const float4*)(t2 + (size_t)(b*C5c+c)*SPc + sjf*32 + f8*4);
    float a1 = sA[c], b1 = sB[c];
    float4 y;
    y.x = fmaf(v.x, a1, b1); y.x = y.x>=0.f ? y.x : al*y.x;
    y.y = fmaf(v.y, a1, b1); y.y = y.y>=0.f ? y.y : al*y.y;
    y.z = fmaf(v.z, a1, b1); y.z = y.z>=0.f ? y.z : al*y.z;
    y.w = fmaf(v.w, a1, b1); y.w = y.w>=0.f ? y.w : al*y.w;
    *(float4*)(&li[c*32 + f8*4]) = y;
  }
  __syncthreads();
  int sq = tid & 15, oj = tid >> 4;   // 2 px per sq, 4 outs per oj (4-way gather)
  float acc[2][4];
  #pragma unroll
  for(int k=0;k<2;k++)
    #pragma unroll
    for(int j=0;j<4;j++) acc[k][j] = 0.f;
  const float* wb = w + (size_t)(oj*4)*C5c;
  const float* lis = li + sq*2;
  for(int c=0; c<320; c++){
    float h0 = lis[c*32];
    float h1 = lis[c*32+1];
    #pragma unroll
    for(int j=0;j<4;j++){
      float wv = wb[j*C5c + c];
      acc[0][j] = fmaf(h0, wv, acc[0][j]);
      acc[1][j] = fmaf(h1, wv, acc[1][j]);
    }
  }
  #pragma unroll
  for(int j=0;j<4;j++){
    int o = oj*4+j;
    float bv = bias[o];
    float v0 = acc[0][j]+bv, v1 = acc[1][j]+bv;
    *(float2*)(ts + (size_t)(b*64+o)*SPc + sjf*32 + sq*2) = make_float2(v0, v1);
    float sm = v0+v1, sq2 = v0*v0 + v1*v1;
    sm += __shfl_xor(sm,1); sq2 += __shfl_xor(sq2,1);
    sm += __shfl_xor(sm,2); sq2 += __shfl_xor(sq2,2);
    sm += __shfl_xor(sm,4); sq2 += __shfl_xor(sq2,4);
    sm += __shfl_xor(sm,8); sq2 += __shfl_xor(sq2,8);
    if(sq==0){
      pout[o*256 + b*128 + sjf]         = sm;   // P=256
      pout[16384 + o*256 + b*128 + sjf] = sq2;  // CP = 64*256
    }
  }
}

// ---- BN3 (finalized in prologue, P=256) + PReLU3 + residual add into h ----
__global__ void k_addres(const float* __restrict__ ts, float* __restrict__ h,
                         const float* __restrict__ g3, const float* __restrict__ bb3,
                         const float* __restrict__ ap, const float* __restrict__ pin){
  int tid = threadIdx.x;
  int idx = blockIdx.x*256 + tid;
  int c = (idx>>12)&63;              // constant per block
  __shared__ float sAB[2];
  __shared__ float w8[8];
  {
    float S = pin[c*256 + tid];
    float Q = pin[16384 + c*256 + tid];
    #pragma unroll
    for(int d=1; d<64; d<<=1){ S += __shfl_xor(S,d); Q += __shfl_xor(Q,d); }
    int wv = tid>>6, ln = tid&63;
    if(ln==0){ w8[wv] = S; w8[4+wv] = Q; }
    __syncthreads();
    if(tid==0){
      float Sa = (w8[0]+w8[1])+(w8[2]+w8[3]);
      float Qa = (w8[4]+w8[5])+(w8[6]+w8[7]);
      float m = Sa*(1.f/8192.f);
      float var = Qa*(1.f/8192.f) - m*m;
      float r = rsqrtf(var + EPSc);
      float gc = g3[c];
      sAB[0] = gc*r; sAB[1] = bb3[c] - m*gc*r;
    }
    __syncthreads();
  }
  float y = fmaf(ts[idx], sAB[0], sAB[1]);
  float al = ap[0];
  y = y >= 0.f ? y : al*y;
  h[idx] += y;
}

// ---- head v2: 1x1 conv (64->512) -> gvol [b][q][ci][k][o][z=p] ----
__global__ void k_head_t(const float* __restrict__ h, const float* __restrict__ w,
                         const float* __restrict__ bias, float* __restrict__ gv){
  __shared__ float lh[8*65];      // [p8][kc64]
  __shared__ float lw[64*65];     // [cc64][kc64]
  int bid = blockIdx.x;           // (b*64 + q)*8 + pgg
  int pgg = bid & 7, q = (bid>>3) & 63, b = bid >> 9;
  int tid = threadIdx.x;
  for(int t = tid; t < 512; t += 256){
    int p = t >> 6, kc = t & 63;
    lh[p*65 + kc] = h[((size_t)(b*64+kc))*SPc + (pgg*8+p)*64 + q];
  }
  int cc = tid & 63, pp = tid >> 6;     // wave-uniform pp
  float* gb = gv + (size_t)b*(64*16*2048) + ((size_t)q*16)*2048;
  for(int ch = 0; ch < 8; ++ch){
    __syncthreads();
    for(int t = tid; t < 1024; t += 256){
      int rc = t >> 4, f4 = t & 15;
      int combo = ch*64 + rc;
      int ci = combo>>5, kk = (combo>>4)&1, o = combo&15;
      int c0 = (o*16+ci)*2 + kk;
      float4 v = *(const float4*)(w + (size_t)c0*64 + f4*4);
      *(float4*)(&lw[rc*65 + f4*4]) = v;
    }
    __syncthreads();
    int combo = ch*64 + cc;
    int ci = combo>>5, kk = (combo>>4)&1, o = combo&15;
    int c0 = (o*16+ci)*2 + kk;
    float a0 = 0.f, a1 = 0.f;
    const float* lh0 = &lh[(pp*2+0)*65];
    const float* lh1 = &lh[(pp*2+1)*65];
    const float* lwr = &lw[cc*65];
    #pragma unroll 8
    for(int kc=0; kc<64; kc++){
      float wv = lwr[kc];
      a0 = fmaf(lh0[kc], wv, a0);
      a1 = fmaf(lh1[kc], wv, a1);
    }
    float bv = bias[c0];
    float* dst = gb + (size_t)ci*2048 + kk*1024 + o*64 + pgg*8 + pp*2;
    *(float2*)dst = make_float2(a0 + bv, a1 + bv);
  }
}

// ---- slice v5: 17-col segments, lane-transposed (16 lanes = 16 o, 1 px) ----
__global__ void k_slice(const float* __restrict__ x, const float* __restrict__ gv,
                        float* __restrict__ outp, float* __restrict__ pacc){
  __shared__ float lds[8320];     // 4160 float2
  int xseg = blockIdx.x, hp = blockIdx.y, b = blockIdx.z;
  int tid = threadIdx.x;
  const float* gb = gv + (size_t)b*(64*16*2048);
  int y0 = (hp*63)/255;
  int y1 = min(y0+1, 63);
  float fy = hp*(63.f/255.f) - (float)y0;

  if(tid < 128){
    int half = tid & 1, o = (tid>>1)&15, k = (tid>>5)&1, cix = (tid>>6)&1;
    int xs = min(xseg + cix, 15);
    const float* b0p = gb + (size_t)(y0*16+xs)*2048 + k*1024 + o*64;
    const float* b1p = gb + (size_t)(y1*16+xs)*2048 + k*1024 + o*64;
    float2* d = (float2*)lds + cix*2080 + k*1040 + o*65;
    float prev = 0.f;
    if(half){
      float a = b0p[31], c = b1p[31];
      prev = fmaf(fy, c-a, a);
    }
    int j0 = half*8;
    #pragma unroll
    for(int j=0; j<8; ++j){
      int jj = j0 + j;
      float4 a = *(const float4*)(b0p + jj*4);
      float4 c = *(const float4*)(b1p + jj*4);
      float v0 = fmaf(fy, c.x-a.x, a.x);
      float v1 = fmaf(fy, c.y-a.y, a.y);
      float v2 = fmaf(fy, c.z-a.z, a.z);
      float v3 = fmaf(fy, c.w-a.w, a.w);
      if(j > 0 || half) d[4*jj-1] = make_float2(prev, v0);
      d[4*jj]   = make_float2(v0, v1);
      d[4*jj+1] = make_float2(v1, v2);
      d[4*jj+2] = make_float2(v2, v3);
      prev = v3;
    }
    if(half) d[63] = make_float2(prev, prev);
  }
  __syncthreads();

  int wv = tid>>6, lane = tid&63;
  int o = lane & 15, pl = lane >> 4;  // 16 lanes = 16 o of ONE pixel
  int lc = wv*4 + pl;                 // 0..19 (17+ invalid)
  int wq = xseg*17 + lc;
  bool act = (lc < 17) && (wq < 256);
  int wqc = min(wq, 255);

  float fx = (float)lc * (1.f/17.f);
  float cwA = 1.f - fx, cwB = fx;
  int obase = o*65;
  const float2* l2 = (const float2*)lds;

  float acc = 0.f, bacc = 0.f;
  for(int i=0; i<CIc; i++){
    float xv = x[((size_t)(b*CIc+i)*Hc + hp)*Wc + wqc];
    float g = fminf(fmaxf(xv, 0.f), 1.f);
    float pz = g*63.f;
    int z0 = (int)pz; float fz = pz - (float)z0;
    float wz0 = cwA*(1.f-fz), wz1 = cwA*fz;
    float vz0 = cwB*(1.f-fz), vz1 = cwB*fz;
    int aA = obase + z0, aB = 2080 + obase + z0;
    float2 wA = l2[aA],        wB = l2[aB];
    float2 bA = l2[aA + 1040], bB = l2[aB + 1040];
    float wsum = fmaf(wz0, wA.x, fmaf(wz1, wA.y, fmaf(vz0, wB.x, vz1*wB.y)));
    float bsum = fmaf(wz0, bA.x, fmaf(wz1, bA.y, fmaf(vz0, bB.x, vz1*bB.y)));
    acc  = fmaf(xv, wsum, acc);
    bacc += bsum;
  }
  float vout = act ? (acc + bacc*(1.f/16.f)) : 0.f;
  if(act)
    outp[((size_t)(b*COc+o)*Hc + hp)*Wc + wq] = vout;

  float sm = vout, sq = vout*vout;
  sm += __shfl_xor(sm,16); sq += __shfl_xor(sq,16);
  sm += __shfl_xor(sm,32); sq += __shfl_xor(sq,32);
  __syncthreads();
  if(lane < 16){ lds[(wv*16+o)*2] = sm; lds[(wv*16+o)*2+1] = sq; }
  __syncthreads();
  if(tid < 32){
    int oo = tid>>1, kd = tid&1;
    float S = (((lds[(0*16+oo)*2+kd] + lds[(1*16+oo)*2+kd])
             +  (lds[(2*16+oo)*2+kd] + lds[(3*16+oo)*2+kd]))
             +   lds[(4*16+oo)*2+kd]);
    int blk = (b*256 + hp)*16 + xseg;       // P=8192
    pacc[kd*131072 + oo*8192 + blk] = S;    // CP = 16*8192
  }
}

// ---- final BN + SiLU in place on d_out ----
__global__ void k_final(float* __restrict__ out, const float* __restrict__ A,
                        const float* __restrict__ B){
  int idx = blockIdx.x*256 + threadIdx.x;
  int c = (idx>>16)&15;
  float y = fmaf(out[idx], A[c], B[c]);
  out[idx] = y / (1.f + expf(-y));
}

} // namespace

extern "C" void kernel_launch(void* const* d_in, const int* in_sizes, int n_in,
                              void* d_out, int out_size, void* d_ws, size_t ws_size,
                              hipStream_t stream){
  const float* x       = (const float*)d_in[0];
  const float* conv0_w = (const float*)d_in[1];
  const float* conv0_b = (const float*)d_in[2];
  const float* prelu0  = (const float*)d_in[3];
  const float* c1w  = (const float*)d_in[4];
  const float* c1b  = (const float*)d_in[5];
  const float* bn1g = (const float*)d_in[6];
  const float* bn1b = (const float*)d_in[7];
  const float* p1   = (const float*)d_in[8];
  const float* dww  = (const float*)d_in[9];
  const float* dwb  = (const float*)d_in[10];
  const float* bn2g = (const float*)d_in[11];
  const float* bn2b = (const float*)d_in[12];
  const float* p2   = (const float*)d_in[13];
  const float* c3w  = (const float*)d_in[14];
  const float* c3b  = (const float*)d_in[15];
  const float* bn3g = (const float*)d_in[16];
  const float* bn3b = (const float*)d_in[17];
  const float* p3   = (const float*)d_in[18];
  const float* hw   = (const float*)d_in[19];
  const float* hb   = (const float*)d_in[20];
  const float* obg  = (const float*)d_in[21];
  const float* obb  = (const float*)d_in[22];
  float* out = (float*)d_out;
  float* ws  = (float*)d_ws;

  // workspace (floats)
  float* xd    = ws;                 // 131072
  float* h     = xd + 131072;        // 524288
  float* A     = h  + 524288;        // 320
  float* B     = A  + 320;           // 320
  float* pacc  = B  + 320;           // 81920  BN1 partials
  float* paccb = pacc + 81920;       // 20480  BN2 partials
  float* paccc = paccb + 20480;      // 65536  BN3 partials
  float* t1    = paccc + 65536;      // 2621440
  float* t2    = t1 + 2621440;       // 2621440
  float* ts    = t2 + 2621440;       // 524288
  float* gv    = t1;                 // 4194304 aliases t1+t2 (dead by head)
  float* pacc2 = ts;                 // 262144 slice partials alias ts

  k_down <<<512,  256, 0, stream>>>(x, xd);
  k_conv0<<<2048, 256, 0, stream>>>(xd, conv0_w, conv0_b, prelu0, h);

  for(int i=0; i<3; i++){
    k_c1  <<<dim3(4,64,Bn), 256, 0, stream>>>(h, c1w + i*20480, c1b + i*320, t1, pacc);
    k_dw_s<<<10240, 256, 0, stream>>>(t1, dww + i*2880, dwb + i*320,
                                      bn1g+i*320, bn1b+i*320, p1+i, pacc, t2, paccb);
    k_c3f <<<dim3(128,Bn), 256, 0, stream>>>(t2, c3w + i*20480, c3b + i*64,
                                             bn2g+i*320, bn2b+i*320, p2+i, paccb, ts, paccc);
    k_addres<<<2048, 256, 0, stream>>>(ts, h, bn3g+i*64, bn3b+i*64, p3+i, paccc);
  }

  k_head_t<<<1024, 256, 0, stream>>>(h, hw, hb, gv);
  k_slice <<<dim3(16,256,Bn), 320, 0, stream>>>(x, gv, out, pacc2);
  k_fin   <<<16, 256, 0, stream>>>(pacc2, 8192, 1.f/131072.f, obg, obb, A, B);
  k_final <<<8192, 256, 0, stream>>>(out, A, B);
}

// Round 30
// 288.744 us; speedup vs baseline: 1.5559x; 1.1068x over previous
//
#include <hip/hip_runtime.h>
#include <math.h>

namespace {

constexpr int Bn=2, CIc=16, COc=16, Hc=256, Wc=256, HIDc=64, C5c=320;
constexpr int SPc = 4096;               // 64*64
constexpr float EPSc = 1e-5f;

// ---- 4x4 mean downsample: x (B,16,256,256) -> xd (B,16,64,64) ----
__global__ void k_down(const float* __restrict__ x, float* __restrict__ xd){
  int idx = blockIdx.x*blockDim.x + threadIdx.x;
  if (idx >= Bn*CIc*SPc) return;
  int q = idx & 63, p = (idx>>6)&63, c = idx>>12;
  const float* xp = x + ((size_t)c*Hc + p*4)*Wc + q*4;
  float s = 0.f;
  #pragma unroll
  for(int dy=0; dy<4; dy++)
    #pragma unroll
    for(int dx=0; dx<4; dx++) s += xp[dy*Wc+dx];
  xd[idx] = s * (1.f/16.f);
}

// ---- conv0 3x3 pad1 (16->64) + scalar PReLU ----
__global__ void k_conv0(const float* __restrict__ xd, const float* __restrict__ w,
                        const float* __restrict__ bias, const float* __restrict__ a0,
                        float* __restrict__ h){
  int idx = blockIdx.x*blockDim.x + threadIdx.x;
  if (idx >= Bn*HIDc*SPc) return;
  int q = idx&63, p=(idx>>6)&63, co=(idx>>12)&63, b=idx/(HIDc*SPc);
  float acc = bias[co];
  for(int ci=0; ci<CIc; ci++){
    const float* xp = xd + (size_t)(b*CIc+ci)*SPc;
    const float* wp = w + (co*CIc+ci)*9;
    #pragma unroll
    for(int u=0; u<3; u++){
      int pp = p+u-1; if((unsigned)pp >= 64u) continue;
      #pragma unroll
      for(int v=0; v<3; v++){
        int qq = q+v-1; if((unsigned)qq >= 64u) continue;
        acc = fmaf(xp[pp*64+qq], wp[u*3+v], acc);
      }
    }
  }
  float a = a0[0];
  h[idx] = acc >= 0.f ? acc : a*acc;
}

// ---- fused 1x1 conv 64->320 + BN1 stat partials; 4s x 5o register tile ----
__global__ void k_c1(const float* __restrict__ h, const float* __restrict__ w,
                     const float* __restrict__ bias, float* __restrict__ t1,
                     float* __restrict__ pacc){
  __shared__ float lh[64*64];
  int og = blockIdx.x, sj = blockIdx.y, b = blockIdx.z;
  int tid = threadIdx.x;
  for(int it=0; it<4; ++it){
    int f4 = tid + it*256;               // c*16 + s4
    int c = f4>>4, s4 = f4&15;
    float4 v = *(const float4*)(h + (size_t)(b*64+c)*SPc + sj*64 + s4*4);
    *(float4*)(&lh[c*64 + s4*4]) = v;
  }
  __syncthreads();
  int sq = tid & 15, oj = tid >> 4;
  int ob = og*80 + oj*5;
  float acc[4][5];
  #pragma unroll
  for(int k=0;k<4;k++)
    #pragma unroll
    for(int j=0;j<5;j++) acc[k][j] = 0.f;
  const float* lhs = lh + sq*4;
  for(int c=0;c<64;c++){
    float h0 = lhs[c*64+0];
    float h1 = lhs[c*64+1];
    float h2 = lhs[c*64+2];
    float h3 = lhs[c*64+3];
    #pragma unroll
    for(int j=0;j<5;j++){
      float wv = w[(ob+j)*64 + c];
      acc[0][j] = fmaf(h0, wv, acc[0][j]);
      acc[1][j] = fmaf(h1, wv, acc[1][j]);
      acc[2][j] = fmaf(h2, wv, acc[2][j]);
      acc[3][j] = fmaf(h3, wv, acc[3][j]);
    }
  }
  #pragma unroll
  for(int j=0;j<5;j++){
    int o = ob + j;
    float bv = bias[o];
    float4 v4 = make_float4(acc[0][j]+bv, acc[1][j]+bv, acc[2][j]+bv, acc[3][j]+bv);
    *(float4*)(t1 + (size_t)(b*320+o)*SPc + sj*64 + sq*4) = v4;
    float sm  = (v4.x+v4.y)+(v4.z+v4.w);
    float sq2 = (v4.x*v4.x + v4.y*v4.y) + (v4.z*v4.z + v4.w*v4.w);
    sm += __shfl_xor(sm,1); sq2 += __shfl_xor(sq2,1);
    sm += __shfl_xor(sm,2); sq2 += __shfl_xor(sq2,2);
    sm += __shfl_xor(sm,4); sq2 += __shfl_xor(sq2,4);
    sm += __shfl_xor(sm,8); sq2 += __shfl_xor(sq2,8);
    if(sq==0){
      pacc[o*128 + b*64 + sj]         = sm;   // P=128
      pacc[40960 + o*128 + b*64 + sj] = sq2;  // CP = 320*128
    }
  }
}

// ---- finalize (out-BN only): partials -> A,B ----
__global__ void k_fin(const float* __restrict__ pacc, int P, float invN,
                      const float* __restrict__ g, const float* __restrict__ bb,
                      float* __restrict__ A, float* __restrict__ B){
  __shared__ double sh[256], sh2[256];
  int c = blockIdx.x, C = gridDim.x, tid = threadIdx.x;
  double s=0.0, s2=0.0;
  for(int p=tid; p<P; p+=256){
    s  += (double)pacc[c*P+p];
    s2 += (double)pacc[C*P + c*P + p];
  }
  sh[tid]=s; sh2[tid]=s2; __syncthreads();
  for(int off=128; off>0; off>>=1){
    if(tid<off){ sh[tid]+=sh[tid+off]; sh2[tid]+=sh2[tid+off]; }
    __syncthreads();
  }
  if(tid==0){
    float m = (float)(sh[0]*(double)invN);
    float v = (float)(sh2[0]*(double)invN) - m*m;
    float r = rsqrtf(v + EPSc);
    float gc = g[c];
    A[c] = gc*r;
    B[c] = bb[c] - m*gc*r;
  }
}

// ---- depthwise 3x3 v2: one (b,c) 64x64 plane per block, LDS-tiled ----
// grid 640 = b*320+c, 256 thr, 16 px/thread. BN1 applied ONCE at staging.
// BN2 partial: one (S,Q) per block -> P=2 layout pout[c*2+b], CP=320*2.
__global__ void k_dw_s(const float* __restrict__ t1, const float* __restrict__ w,
                       const float* __restrict__ bias, const float* __restrict__ g1,
                       const float* __restrict__ bb1, const float* __restrict__ ap,
                       const float* __restrict__ pin, float* __restrict__ t2,
                       float* __restrict__ pout){
  __shared__ float lt[64*65];     // padded plane, 16.25 KB
  int bid = blockIdx.x;
  int c = bid % C5c, b = bid / C5c;
  int tid = threadIdx.x;
  __shared__ float sAB[2];
  __shared__ float ws4[4];
  {
    float v = (tid<128) ? pin[c*128 + tid] : pin[40960 + c*128 + (tid-128)];
    #pragma unroll
    for(int d=1; d<64; d<<=1) v += __shfl_xor(v, d);
    int wv = tid>>6, ln = tid&63;
    if(ln==0) ws4[wv] = v;
    __syncthreads();
    if(tid==0){
      float S = ws4[0]+ws4[1], Q = ws4[2]+ws4[3];
      float m = S*(1.f/8192.f);
      float var = Q*(1.f/8192.f) - m*m;
      float r = rsqrtf(var + EPSc);
      float gc = g1[c];
      sAB[0] = gc*r; sAB[1] = bb1[c] - m*gc*r;
    }
    __syncthreads();
  }
  float a1 = sAB[0], b1 = sAB[1], al = ap[0];
  const float* ip = t1 + (size_t)(b*C5c+c)*SPc;
  // stage + BN1+PReLU1 once per element: 4 float4 per thread
  for(int t = tid; t < 1024; t += 256){
    int p = t >> 4, f4 = t & 15;
    float4 v = *(const float4*)(ip + p*64 + f4*4);
    float4 y;
    y.x = fmaf(v.x, a1, b1); y.x = y.x>=0.f ? y.x : al*y.x;
    y.y = fmaf(v.y, a1, b1); y.y = y.y>=0.f ? y.y : al*y.y;
    y.z = fmaf(v.z, a1, b1); y.z = y.z>=0.f ? y.z : al*y.z;
    y.w = fmaf(v.w, a1, b1); y.w = y.w>=0.f ? y.w : al*y.w;
    *(float4*)(&lt[p*65 + f4*4]) = y;
  }
  const float* wp = w + c*9;
  float w00=wp[0], w01=wp[1], w02=wp[2],
        w10=wp[3], w11=wp[4], w12=wp[5],
        w20=wp[6], w21=wp[7], w22=wp[8];
  float bv = bias[c];
  __syncthreads();
  // 16 px per thread: 4 rows x 4 cols tile; thread t -> rows (t>>4)*4.., cols (t&15)*4..
  int r0 = (tid >> 4) * 4, q0 = (tid & 15) * 4;
  float sm = 0.f, sq2 = 0.f;
  float* op = t2 + (size_t)(b*C5c+c)*SPc;
  #pragma unroll
  for(int dr=0; dr<4; ++dr){
    int p = r0 + dr;
    #pragma unroll
    for(int dq=0; dq<4; ++dq){
      int q = q0 + dq;
      float acc = bv;
      #pragma unroll
      for(int u=0; u<3; u++){
        int pp = p+u-1; if((unsigned)pp >= 64u) continue;
        const float* lr = &lt[pp*65];
        float wr0 = (u==0)?w00:(u==1)?w10:w20;
        float wr1 = (u==0)?w01:(u==1)?w11:w21;
        float wr2 = (u==0)?w02:(u==1)?w12:w22;
        if(q >= 1)  acc = fmaf(lr[q-1], wr0, acc);
        acc = fmaf(lr[q], wr1, acc);
        if(q <= 62) acc = fmaf(lr[q+1], wr2, acc);
      }
      op[p*64 + q] = acc;
      sm += acc; sq2 += acc*acc;
    }
  }
  #pragma unroll
  for(int d=1; d<64; d<<=1){ sm += __shfl_xor(sm,d); sq2 += __shfl_xor(sq2,d); }
  __shared__ float sred[8];
  int wv = tid>>6, ln = tid&63;
  if(ln==0){ sred[wv]=sm; sred[4+wv]=sq2; }
  __syncthreads();
  if(tid==0){
    float S = ((sred[0]+sred[1])+(sred[2]+sred[3]));
    float Q = ((sred[4]+sred[5])+(sred[6]+sred[7]));
    pout[c*2 + b]       = S;   // P=2
    pout[640 + c*2 + b] = Q;   // CP = 320*2
  }
}

// ---- full-K 1x1 conv 320->64 v2: 32 px/block, 2px x 4o register tile ----
// BN2 finalize from P=2 partials; BN3 partials P=256.
__global__ void k_c3f(const float* __restrict__ t2, const float* __restrict__ w,
                      const float* __restrict__ bias, const float* __restrict__ g2,
                      const float* __restrict__ bb2, const float* __restrict__ ap,
                      const float* __restrict__ pin, float* __restrict__ ts,
                      float* __restrict__ pout){
  __shared__ float sA[320], sB[320];
  __shared__ float li[320*32];    // 40 KB
  int sjf = blockIdx.x, b = blockIdx.y;
  int tid = threadIdx.x;
  for(int c = tid; c < 320; c += 256){
    float S = pin[c*2] + pin[c*2+1];
    float Q = pin[640 + c*2] + pin[640 + c*2+1];
    float m = S*(1.f/8192.f);
    float var = Q*(1.f/8192.f) - m*m;
    float r = rsqrtf(var + EPSc);
    float gc = g2[c];
    sA[c] = gc*r; sB[c] = bb2[c] - m*gc*r;
  }
  __syncthreads();
  float al = ap[0];
  for(int t = tid; t < 2560; t += 256){
    int c = t>>3, f8 = t&7;
    float4 v = *(const float4*)(t2 + (size_t)(b*C5c+c)*SPc + sjf*32 + f8*4);
    float a1 = sA[c], b1 = sB[c];
    float4 y;
    y.x = fmaf(v.x, a1, b1); y.x = y.x>=0.f ? y.x : al*y.x;
    y.y = fmaf(v.y, a1, b1); y.y = y.y>=0.f ? y.y : al*y.y;
    y.z = fmaf(v.z, a1, b1); y.z = y.z>=0.f ? y.z : al*y.z;
    y.w = fmaf(v.w, a1, b1); y.w = y.w>=0.f ? y.w : al*y.w;
    *(float4*)(&li[c*32 + f8*4]) = y;
  }
  __syncthreads();
  int sq = tid & 15, oj = tid >> 4;
  float acc[2][4];
  #pragma unroll
  for(int k=0;k<2;k++)
    #pragma unroll
    for(int j=0;j<4;j++) acc[k][j] = 0.f;
  const float* wb = w + (size_t)(oj*4)*C5c;
  const float* lis = li + sq*2;
  for(int c=0; c<320; c++){
    float h0 = lis[c*32];
    float h1 = lis[c*32+1];
    #pragma unroll
    for(int j=0;j<4;j++){
      float wv = wb[j*C5c + c];
      acc[0][j] = fmaf(h0, wv, acc[0][j]);
      acc[1][j] = fmaf(h1, wv, acc[1][j]);
    }
  }
  #pragma unroll
  for(int j=0;j<4;j++){
    int o = oj*4+j;
    float bv = bias[o];
    float v0 = acc[0][j]+bv, v1 = acc[1][j]+bv;
    *(float2*)(ts + (size_t)(b*64+o)*SPc + sjf*32 + sq*2) = make_float2(v0, v1);
    float sm = v0+v1, sq2 = v0*v0 + v1*v1;
    sm += __shfl_xor(sm,1); sq2 += __shfl_xor(sq2,1);
    sm += __shfl_xor(sm,2); sq2 += __shfl_xor(sq2,2);
    sm += __shfl_xor(sm,4); sq2 += __shfl_xor(sq2,4);
    sm += __shfl_xor(sm,8); sq2 += __shfl_xor(sq2,8);
    if(sq==0){
      pout[o*256 + b*128 + sjf]         = sm;   // P=256
      pout[16384 + o*256 + b*128 + sjf] = sq2;  // CP = 64*256
    }
  }
}

// ---- BN3 (finalized in prologue, P=256) + PReLU3 + residual add into h ----
__global__ void k_addres(const float* __restrict__ ts, float* __restrict__ h,
                         const float* __restrict__ g3, const float* __restrict__ bb3,
                         const float* __restrict__ ap, const float* __restrict__ pin){
  int tid = threadIdx.x;
  int idx = blockIdx.x*256 + tid;
  int c = (idx>>12)&63;              // constant per block
  __shared__ float sAB[2];
  __shared__ float w8[8];
  {
    float S = pin[c*256 + tid];
    float Q = pin[16384 + c*256 + tid];
    #pragma unroll
    for(int d=1; d<64; d<<=1){ S += __shfl_xor(S,d); Q += __shfl_xor(Q,d); }
    int wv = tid>>6, ln = tid&63;
    if(ln==0){ w8[wv] = S; w8[4+wv] = Q; }
    __syncthreads();
    if(tid==0){
      float Sa = (w8[0]+w8[1])+(w8[2]+w8[3]);
      float Qa = (w8[4]+w8[5])+(w8[6]+w8[7]);
      float m = Sa*(1.f/8192.f);
      float var = Qa*(1.f/8192.f) - m*m;
      float r = rsqrtf(var + EPSc);
      float gc = g3[c];
      sAB[0] = gc*r; sAB[1] = bb3[c] - m*gc*r;
    }
    __syncthreads();
  }
  float y = fmaf(ts[idx], sAB[0], sAB[1]);
  float al = ap[0];
  y = y >= 0.f ? y : al*y;
  h[idx] += y;
}

// ---- head v2: 1x1 conv (64->512) -> gvol [b][q][ci][k][o][z=p] ----
__global__ void k_head_t(const float* __restrict__ h, const float* __restrict__ w,
                         const float* __restrict__ bias, float* __restrict__ gv){
  __shared__ float lh[8*65];      // [p8][kc64]
  __shared__ float lw[64*65];     // [cc64][kc64]
  int bid = blockIdx.x;           // (b*64 + q)*8 + pgg
  int pgg = bid & 7, q = (bid>>3) & 63, b = bid >> 9;
  int tid = threadIdx.x;
  for(int t = tid; t < 512; t += 256){
    int p = t >> 6, kc = t & 63;
    lh[p*65 + kc] = h[((size_t)(b*64+kc))*SPc + (pgg*8+p)*64 + q];
  }
  int cc = tid & 63, pp = tid >> 6;     // wave-uniform pp
  float* gb = gv + (size_t)b*(64*16*2048) + ((size_t)q*16)*2048;
  for(int ch = 0; ch < 8; ++ch){
    __syncthreads();
    for(int t = tid; t < 1024; t += 256){
      int rc = t >> 4, f4 = t & 15;
      int combo = ch*64 + rc;
      int ci = combo>>5, kk = (combo>>4)&1, o = combo&15;
      int c0 = (o*16+ci)*2 + kk;
      float4 v = *(const float4*)(w + (size_t)c0*64 + f4*4);
      *(float4*)(&lw[rc*65 + f4*4]) = v;
    }
    __syncthreads();
    int combo = ch*64 + cc;
    int ci = combo>>5, kk = (combo>>4)&1, o = combo&15;
    int c0 = (o*16+ci)*2 + kk;
    float a0 = 0.f, a1 = 0.f;
    const float* lh0 = &lh[(pp*2+0)*65];
    const float* lh1 = &lh[(pp*2+1)*65];
    const float* lwr = &lw[cc*65];
    #pragma unroll 8
    for(int kc=0; kc<64; kc++){
      float wv = lwr[kc];
      a0 = fmaf(lh0[kc], wv, a0);
      a1 = fmaf(lh1[kc], wv, a1);
    }
    float bv = bias[c0];
    float* dst = gb + (size_t)ci*2048 + kk*1024 + o*64 + pgg*8 + pp*2;
    *(float2*)dst = make_float2(a0 + bv, a1 + bv);
  }
}

// ---- slice v5: 17-col segments, lane-transposed (16 lanes = 16 o, 1 px) ----
__global__ void k_slice(const float* __restrict__ x, const float* __restrict__ gv,
                        float* __restrict__ outp, float* __restrict__ pacc){
  __shared__ float lds[8320];     // 4160 float2
  int xseg = blockIdx.x, hp = blockIdx.y, b = blockIdx.z;
  int tid = threadIdx.x;
  const float* gb = gv + (size_t)b*(64*16*2048);
  int y0 = (hp*63)/255;
  int y1 = min(y0+1, 63);
  float fy = hp*(63.f/255.f) - (float)y0;

  if(tid < 128){
    int half = tid & 1, o = (tid>>1)&15, k = (tid>>5)&1, cix = (tid>>6)&1;
    int xs = min(xseg + cix, 15);
    const float* b0p = gb + (size_t)(y0*16+xs)*2048 + k*1024 + o*64;
    const float* b1p = gb + (size_t)(y1*16+xs)*2048 + k*1024 + o*64;
    float2* d = (float2*)lds + cix*2080 + k*1040 + o*65;
    float prev = 0.f;
    if(half){
      float a = b0p[31], c = b1p[31];
      prev = fmaf(fy, c-a, a);
    }
    int j0 = half*8;
    #pragma unroll
    for(int j=0; j<8; ++j){
      int jj = j0 + j;
      float4 a = *(const float4*)(b0p + jj*4);
      float4 c = *(const float4*)(b1p + jj*4);
      float v0 = fmaf(fy, c.x-a.x, a.x);
      float v1 = fmaf(fy, c.y-a.y, a.y);
      float v2 = fmaf(fy, c.z-a.z, a.z);
      float v3 = fmaf(fy, c.w-a.w, a.w);
      if(j > 0 || half) d[4*jj-1] = make_float2(prev, v0);
      d[4*jj]   = make_float2(v0, v1);
      d[4*jj+1] = make_float2(v1, v2);
      d[4*jj+2] = make_float2(v2, v3);
      prev = v3;
    }
    if(half) d[63] = make_float2(prev, prev);
  }
  __syncthreads();

  int wv = tid>>6, lane = tid&63;
  int o = lane & 15, pl = lane >> 4;  // 16 lanes = 16 o of ONE pixel
  int lc = wv*4 + pl;                 // 0..19 (17+ invalid)
  int wq = xseg*17 + lc;
  bool act = (lc < 17) && (wq < 256);
  int wqc = min(wq, 255);

  float fx = (float)lc * (1.f/17.f);
  float cwA = 1.f - fx, cwB = fx;
  int obase = o*65;
  const float2* l2 = (const float2*)lds;

  float acc = 0.f, bacc = 0.f;
  for(int i=0; i<CIc; i++){
    float xv = x[((size_t)(b*CIc+i)*Hc + hp)*Wc + wqc];
    float g = fminf(fmaxf(xv, 0.f), 1.f);
    float pz = g*63.f;
    int z0 = (int)pz; float fz = pz - (float)z0;
    float wz0 = cwA*(1.f-fz), wz1 = cwA*fz;
    float vz0 = cwB*(1.f-fz), vz1 = cwB*fz;
    int aA = obase + z0, aB = 2080 + obase + z0;
    float2 wA = l2[aA],        wB = l2[aB];
    float2 bA = l2[aA + 1040], bB = l2[aB + 1040];
    float wsum = fmaf(wz0, wA.x, fmaf(wz1, wA.y, fmaf(vz0, wB.x, vz1*wB.y)));
    float bsum = fmaf(wz0, bA.x, fmaf(wz1, bA.y, fmaf(vz0, bB.x, vz1*bB.y)));
    acc  = fmaf(xv, wsum, acc);
    bacc += bsum;
  }
  float vout = act ? (acc + bacc*(1.f/16.f)) : 0.f;
  if(act)
    outp[((size_t)(b*COc+o)*Hc + hp)*Wc + wq] = vout;

  float sm = vout, sq = vout*vout;
  sm += __shfl_xor(sm,16); sq += __shfl_xor(sq,16);
  sm += __shfl_xor(sm,32); sq += __shfl_xor(sq,32);
  __syncthreads();
  if(lane < 16){ lds[(wv*16+o)*2] = sm; lds[(wv*16+o)*2+1] = sq; }
  __syncthreads();
  if(tid < 32){
    int oo = tid>>1, kd = tid&1;
    float S = (((lds[(0*16+oo)*2+kd] + lds[(1*16+oo)*2+kd])
             +  (lds[(2*16+oo)*2+kd] + lds[(3*16+oo)*2+kd]))
             +   lds[(4*16+oo)*2+kd]);
    int blk = (b*256 + hp)*16 + xseg;       // P=8192
    pacc[kd*131072 + oo*8192 + blk] = S;    // CP = 16*8192
  }
}

// ---- final BN + SiLU in place on d_out ----
__global__ void k_final(float* __restrict__ out, const float* __restrict__ A,
                        const float* __restrict__ B){
  int idx = blockIdx.x*256 + threadIdx.x;
  int c = (idx>>16)&15;
  float y = fmaf(out[idx], A[c], B[c]);
  out[idx] = y / (1.f + expf(-y));
}

} // namespace

extern "C" void kernel_launch(void* const* d_in, const int* in_sizes, int n_in,
                              void* d_out, int out_size, void* d_ws, size_t ws_size,
                              hipStream_t stream){
  const float* x       = (const float*)d_in[0];
  const float* conv0_w = (const float*)d_in[1];
  const float* conv0_b = (const float*)d_in[2];
  const float* prelu0  = (const float*)d_in[3];
  const float* c1w  = (const float*)d_in[4];
  const float* c1b  = (const float*)d_in[5];
  const float* bn1g = (const float*)d_in[6];
  const float* bn1b = (const float*)d_in[7];
  const float* p1   = (const float*)d_in[8];
  const float* dww  = (const float*)d_in[9];
  const float* dwb  = (const float*)d_in[10];
  const float* bn2g = (const float*)d_in[11];
  const float* bn2b = (const float*)d_in[12];
  const float* p2   = (const float*)d_in[13];
  const float* c3w  = (const float*)d_in[14];
  const float* c3b  = (const float*)d_in[15];
  const float* bn3g = (const float*)d_in[16];
  const float* bn3b = (const float*)d_in[17];
  const float* p3   = (const float*)d_in[18];
  const float* hw   = (const float*)d_in[19];
  const float* hb   = (const float*)d_in[20];
  const float* obg  = (const float*)d_in[21];
  const float* obb  = (const float*)d_in[22];
  float* out = (float*)d_out;
  float* ws  = (float*)d_ws;

  // workspace (floats)
  float* xd    = ws;                 // 131072
  float* h     = xd + 131072;        // 524288
  float* A     = h  + 524288;        // 320
  float* B     = A  + 320;           // 320
  float* pacc  = B  + 320;           // 81920  BN1 partials
  float* paccb = pacc + 81920;       // 20480  BN2 partials (P=2 uses first 1280)
  float* paccc = paccb + 20480;      // 65536  BN3 partials
  float* t1    = paccc + 65536;      // 2621440
  float* t2    = t1 + 2621440;       // 2621440
  float* ts    = t2 + 2621440;       // 524288
  float* gv    = t1;                 // 4194304 aliases t1+t2 (dead by head)
  float* pacc2 = ts;                 // 262144 slice partials alias ts

  k_down <<<512,  256, 0, stream>>>(x, xd);
  k_conv0<<<2048, 256, 0, stream>>>(xd, conv0_w, conv0_b, prelu0, h);

  for(int i=0; i<3; i++){
    k_c1  <<<dim3(4,64,Bn), 256, 0, stream>>>(h, c1w + i*20480, c1b + i*320, t1, pacc);
    k_dw_s<<<640, 256, 0, stream>>>(t1, dww + i*2880, dwb + i*320,
                                    bn1g+i*320, bn1b+i*320, p1+i, pacc, t2, paccb);
    k_c3f <<<dim3(128,Bn), 256, 0, stream>>>(t2, c3w + i*20480, c3b + i*64,
                                             bn2g+i*320, bn2b+i*320, p2+i, paccb, ts, paccc);
    k_addres<<<2048, 256, 0, stream>>>(ts, h, bn3g+i*64, bn3b+i*64, p3+i, paccc);
  }

  k_head_t<<<1024, 256, 0, stream>>>(h, hw, hb, gv);
  k_slice <<<dim3(16,256,Bn), 320, 0, stream>>>(x, gv, out, pacc2);
  k_fin   <<<16, 256, 0, stream>>>(pacc2, 8192, 1.f/131072.f, obg, obb, A, B);
  k_final <<<8192, 256, 0, stream>>>(out, A, B);
}

// Round 31
// 281.308 us; speedup vs baseline: 1.5971x; 1.0264x over previous
//
#include <hip/hip_runtime.h>
#include <math.h>

namespace {

constexpr int Bn=2, CIc=16, COc=16, Hc=256, Wc=256, HIDc=64, C5c=320;
constexpr int SPc = 4096;               // 64*64
constexpr float EPSc = 1e-5f;

// ---- 4x4 mean downsample: x (B,16,256,256) -> xd (B,16,64,64) ----
__global__ void k_down(const float* __restrict__ x, float* __restrict__ xd){
  int idx = blockIdx.x*blockDim.x + threadIdx.x;
  if (idx >= Bn*CIc*SPc) return;
  int q = idx & 63, p = (idx>>6)&63, c = idx>>12;
  const float* xp = x + ((size_t)c*Hc + p*4)*Wc + q*4;
  float s = 0.f;
  #pragma unroll
  for(int dy=0; dy<4; dy++)
    #pragma unroll
    for(int dx=0; dx<4; dx++) s += xp[dy*Wc+dx];
  xd[idx] = s * (1.f/16.f);
}

// ---- conv0 v2: 3x3 pad1 (16->64) + PReLU, 4-px register tile ----
// thread = (b, co, p, qg): q0=qg*4; co wave-uniform -> scalar weight loads.
// Per ci: 18 xd loads (3 rows x 6-wide window) feed 36 FMA.
__global__ void k_conv0(const float* __restrict__ xd, const float* __restrict__ w,
                        const float* __restrict__ bias, const float* __restrict__ a0,
                        float* __restrict__ h){
  int idx = blockIdx.x*blockDim.x + threadIdx.x;   // 131072 total
  int qg = idx & 15, p = (idx>>4)&63, co = (idx>>10)&63, b = idx>>16;
  int q0 = qg*4;
  float acc0, acc1, acc2, acc3;
  float bv = bias[co];
  acc0 = acc1 = acc2 = acc3 = bv;
  for(int ci=0; ci<CIc; ci++){
    const float* xp = xd + (size_t)(b*CIc+ci)*SPc;
    const float* wp = w + (co*CIc+ci)*9;
    #pragma unroll
    for(int u=0; u<3; u++){
      int pp = p+u-1;
      if((unsigned)pp >= 64u) continue;
      const float* xr = xp + pp*64;
      float4 m = *(const float4*)(xr + q0);
      float lft = (q0 > 0)  ? xr[q0-1] : 0.f;
      float rgt = (q0 < 60) ? xr[q0+4] : 0.f;
      float w0 = wp[u*3+0], w1 = wp[u*3+1], w2 = wp[u*3+2];
      acc0 = fmaf(lft, w0, acc0); acc0 = fmaf(m.x, w1, acc0); acc0 = fmaf(m.y, w2, acc0);
      acc1 = fmaf(m.x, w0, acc1); acc1 = fmaf(m.y, w1, acc1); acc1 = fmaf(m.z, w2, acc1);
      acc2 = fmaf(m.y, w0, acc2); acc2 = fmaf(m.z, w1, acc2); acc2 = fmaf(m.w, w2, acc2);
      acc3 = fmaf(m.z, w0, acc3); acc3 = fmaf(m.w, w1, acc3); acc3 = fmaf(rgt, w2, acc3);
    }
  }
  float a = a0[0];
  float4 o4;
  o4.x = acc0 >= 0.f ? acc0 : a*acc0;
  o4.y = acc1 >= 0.f ? acc1 : a*acc1;
  o4.z = acc2 >= 0.f ? acc2 : a*acc2;
  o4.w = acc3 >= 0.f ? acc3 : a*acc3;
  *(float4*)(h + (size_t)(b*HIDc+co)*SPc + p*64 + q0) = o4;
}

// ---- fused 1x1 conv 64->320 + BN1 stat partials; 4s x 5o register tile ----
__global__ void k_c1(const float* __restrict__ h, const float* __restrict__ w,
                     const float* __restrict__ bias, float* __restrict__ t1,
                     float* __restrict__ pacc){
  __shared__ float lh[64*64];
  int og = blockIdx.x, sj = blockIdx.y, b = blockIdx.z;
  int tid = threadIdx.x;
  for(int it=0; it<4; ++it){
    int f4 = tid + it*256;               // c*16 + s4
    int c = f4>>4, s4 = f4&15;
    float4 v = *(const float4*)(h + (size_t)(b*64+c)*SPc + sj*64 + s4*4);
    *(float4*)(&lh[c*64 + s4*4]) = v;
  }
  __syncthreads();
  int sq = tid & 15, oj = tid >> 4;
  int ob = og*80 + oj*5;
  float acc[4][5];
  #pragma unroll
  for(int k=0;k<4;k++)
    #pragma unroll
    for(int j=0;j<5;j++) acc[k][j] = 0.f;
  const float* lhs = lh + sq*4;
  for(int c=0;c<64;c++){
    float h0 = lhs[c*64+0];
    float h1 = lhs[c*64+1];
    float h2 = lhs[c*64+2];
    float h3 = lhs[c*64+3];
    #pragma unroll
    for(int j=0;j<5;j++){
      float wv = w[(ob+j)*64 + c];
      acc[0][j] = fmaf(h0, wv, acc[0][j]);
      acc[1][j] = fmaf(h1, wv, acc[1][j]);
      acc[2][j] = fmaf(h2, wv, acc[2][j]);
      acc[3][j] = fmaf(h3, wv, acc[3][j]);
    }
  }
  #pragma unroll
  for(int j=0;j<5;j++){
    int o = ob + j;
    float bv = bias[o];
    float4 v4 = make_float4(acc[0][j]+bv, acc[1][j]+bv, acc[2][j]+bv, acc[3][j]+bv);
    *(float4*)(t1 + (size_t)(b*320+o)*SPc + sj*64 + sq*4) = v4;
    float sm  = (v4.x+v4.y)+(v4.z+v4.w);
    float sq2 = (v4.x*v4.x + v4.y*v4.y) + (v4.z*v4.z + v4.w*v4.w);
    sm += __shfl_xor(sm,1); sq2 += __shfl_xor(sq2,1);
    sm += __shfl_xor(sm,2); sq2 += __shfl_xor(sq2,2);
    sm += __shfl_xor(sm,4); sq2 += __shfl_xor(sq2,4);
    sm += __shfl_xor(sm,8); sq2 += __shfl_xor(sq2,8);
    if(sq==0){
      pacc[o*128 + b*64 + sj]         = sm;   // P=128
      pacc[40960 + o*128 + b*64 + sj] = sq2;  // CP = 320*128
    }
  }
}

// ---- finalize (out-BN only): partials -> A,B ----
__global__ void k_fin(const float* __restrict__ pacc, int P, float invN,
                      const float* __restrict__ g, const float* __restrict__ bb,
                      float* __restrict__ A, float* __restrict__ B){
  __shared__ double sh[256], sh2[256];
  int c = blockIdx.x, C = gridDim.x, tid = threadIdx.x;
  double s=0.0, s2=0.0;
  for(int p=tid; p<P; p+=256){
    s  += (double)pacc[c*P+p];
    s2 += (double)pacc[C*P + c*P + p];
  }
  sh[tid]=s; sh2[tid]=s2; __syncthreads();
  for(int off=128; off>0; off>>=1){
    if(tid<off){ sh[tid]+=sh[tid+off]; sh2[tid]+=sh2[tid+off]; }
    __syncthreads();
  }
  if(tid==0){
    float m = (float)(sh[0]*(double)invN);
    float v = (float)(sh2[0]*(double)invN) - m*m;
    float r = rsqrtf(v + EPSc);
    float gc = g[c];
    A[c] = gc*r;
    B[c] = bb[c] - m*gc*r;
  }
}

// ---- depthwise 3x3 v2: one (b,c) 64x64 plane per block, LDS-tiled ----
__global__ void k_dw_s(const float* __restrict__ t1, const float* __restrict__ w,
                       const float* __restrict__ bias, const float* __restrict__ g1,
                       const float* __restrict__ bb1, const float* __restrict__ ap,
                       const float* __restrict__ pin, float* __restrict__ t2,
                       float* __restrict__ pout){
  __shared__ float lt[64*65];     // padded plane, 16.25 KB
  int bid = blockIdx.x;
  int c = bid % C5c, b = bid / C5c;
  int tid = threadIdx.x;
  __shared__ float sAB[2];
  __shared__ float ws4[4];
  {
    float v = (tid<128) ? pin[c*128 + tid] : pin[40960 + c*128 + (tid-128)];
    #pragma unroll
    for(int d=1; d<64; d<<=1) v += __shfl_xor(v, d);
    int wv = tid>>6, ln = tid&63;
    if(ln==0) ws4[wv] = v;
    __syncthreads();
    if(tid==0){
      float S = ws4[0]+ws4[1], Q = ws4[2]+ws4[3];
      float m = S*(1.f/8192.f);
      float var = Q*(1.f/8192.f) - m*m;
      float r = rsqrtf(var + EPSc);
      float gc = g1[c];
      sAB[0] = gc*r; sAB[1] = bb1[c] - m*gc*r;
    }
    __syncthreads();
  }
  float a1 = sAB[0], b1 = sAB[1], al = ap[0];
  const float* ip = t1 + (size_t)(b*C5c+c)*SPc;
  for(int t = tid; t < 1024; t += 256){
    int p = t >> 4, f4 = t & 15;
    float4 v = *(const float4*)(ip + p*64 + f4*4);
    float4 y;
    y.x = fmaf(v.x, a1, b1); y.x = y.x>=0.f ? y.x : al*y.x;
    y.y = fmaf(v.y, a1, b1); y.y = y.y>=0.f ? y.y : al*y.y;
    y.z = fmaf(v.z, a1, b1); y.z = y.z>=0.f ? y.z : al*y.z;
    y.w = fmaf(v.w, a1, b1); y.w = y.w>=0.f ? y.w : al*y.w;
    *(float4*)(&lt[p*65 + f4*4]) = y;
  }
  const float* wp = w + c*9;
  float w00=wp[0], w01=wp[1], w02=wp[2],
        w10=wp[3], w11=wp[4], w12=wp[5],
        w20=wp[6], w21=wp[7], w22=wp[8];
  float bv = bias[c];
  __syncthreads();
  int r0 = (tid >> 4) * 4, q0 = (tid & 15) * 4;
  float sm = 0.f, sq2 = 0.f;
  float* op = t2 + (size_t)(b*C5c+c)*SPc;
  #pragma unroll
  for(int dr=0; dr<4; ++dr){
    int p = r0 + dr;
    #pragma unroll
    for(int dq=0; dq<4; ++dq){
      int q = q0 + dq;
      float acc = bv;
      #pragma unroll
      for(int u=0; u<3; u++){
        int pp = p+u-1; if((unsigned)pp >= 64u) continue;
        const float* lr = &lt[pp*65];
        float wr0 = (u==0)?w00:(u==1)?w10:w20;
        float wr1 = (u==0)?w01:(u==1)?w11:w21;
        float wr2 = (u==0)?w02:(u==1)?w12:w22;
        if(q >= 1)  acc = fmaf(lr[q-1], wr0, acc);
        acc = fmaf(lr[q], wr1, acc);
        if(q <= 62) acc = fmaf(lr[q+1], wr2, acc);
      }
      op[p*64 + q] = acc;
      sm += acc; sq2 += acc*acc;
    }
  }
  #pragma unroll
  for(int d=1; d<64; d<<=1){ sm += __shfl_xor(sm,d); sq2 += __shfl_xor(sq2,d); }
  __shared__ float sred[8];
  int wv = tid>>6, ln = tid&63;
  if(ln==0){ sred[wv]=sm; sred[4+wv]=sq2; }
  __syncthreads();
  if(tid==0){
    float S = ((sred[0]+sred[1])+(sred[2]+sred[3]));
    float Q = ((sred[4]+sred[5])+(sred[6]+sred[7]));
    pout[c*2 + b]       = S;   // P=2
    pout[640 + c*2 + b] = Q;   // CP = 320*2
  }
}

// ---- full-K 1x1 conv 320->64 v2: 32 px/block, 2px x 4o register tile ----
__global__ void k_c3f(const float* __restrict__ t2, const float* __restrict__ w,
                      const float* __restrict__ bias, const float* __restrict__ g2,
                      const float* __restrict__ bb2, const float* __restrict__ ap,
                      const float* __restrict__ pin, float* __restrict__ ts,
                      float* __restrict__ pout){
  __shared__ float sA[320], sB[320];
  __shared__ float li[320*32];    // 40 KB
  int sjf = blockIdx.x, b = blockIdx.y;
  int tid = threadIdx.x;
  for(int c = tid; c < 320; c += 256){
    float S = pin[c*2] + pin[c*2+1];
    float Q = pin[640 + c*2] + pin[640 + c*2+1];
    float m = S*(1.f/8192.f);
    float var = Q*(1.f/8192.f) - m*m;
    float r = rsqrtf(var + EPSc);
    float gc = g2[c];
    sA[c] = gc*r; sB[c] = bb2[c] - m*gc*r;
  }
  __syncthreads();
  float al = ap[0];
  for(int t = tid; t < 2560; t += 256){
    int c = t>>3, f8 = t&7;
    float4 v = *(const float4*)(t2 + (size_t)(b*C5c+c)*SPc + sjf*32 + f8*4);
    float a1 = sA[c], b1 = sB[c];
    float4 y;
    y.x = fmaf(v.x, a1, b1); y.x = y.x>=0.f ? y.x : al*y.x;
    y.y = fmaf(v.y, a1, b1); y.y = y.y>=0.f ? y.y : al*y.y;
    y.z = fmaf(v.z, a1, b1); y.z = y.z>=0.f ? y.z : al*y.z;
    y.w = fmaf(v.w, a1, b1); y.w = y.w>=0.f ? y.w : al*y.w;
    *(float4*)(&li[c*32 + f8*4]) = y;
  }
  __syncthreads();
  int sq = tid & 15, oj = tid >> 4;
  float acc[2][4];
  #pragma unroll
  for(int k=0;k<2;k++)
    #pragma unroll
    for(int j=0;j<4;j++) acc[k][j] = 0.f;
  const float* wb = w + (size_t)(oj*4)*C5c;
  const float* lis = li + sq*2;
  for(int c=0; c<320; c++){
    float h0 = lis[c*32];
    float h1 = lis[c*32+1];
    #pragma unroll
    for(int j=0;j<4;j++){
      float wv = wb[j*C5c + c];
      acc[0][j] = fmaf(h0, wv, acc[0][j]);
      acc[1][j] = fmaf(h1, wv, acc[1][j]);
    }
  }
  #pragma unroll
  for(int j=0;j<4;j++){
    int o = oj*4+j;
    float bv = bias[o];
    float v0 = acc[0][j]+bv, v1 = acc[1][j]+bv;
    *(float2*)(ts + (size_t)(b*64+o)*SPc + sjf*32 + sq*2) = make_float2(v0, v1);
    float sm = v0+v1, sq2 = v0*v0 + v1*v1;
    sm += __shfl_xor(sm,1); sq2 += __shfl_xor(sq2,1);
    sm += __shfl_xor(sm,2); sq2 += __shfl_xor(sq2,2);
    sm += __shfl_xor(sm,4); sq2 += __shfl_xor(sq2,4);
    sm += __shfl_xor(sm,8); sq2 += __shfl_xor(sq2,8);
    if(sq==0){
      pout[o*256 + b*128 + sjf]         = sm;   // P=256
      pout[16384 + o*256 + b*128 + sjf] = sq2;  // CP = 64*256
    }
  }
}

// ---- BN3 (finalized in prologue, P=256) + PReLU3 + residual add into h ----
__global__ void k_addres(const float* __restrict__ ts, float* __restrict__ h,
                         const float* __restrict__ g3, const float* __restrict__ bb3,
                         const float* __restrict__ ap, const float* __restrict__ pin){
  int tid = threadIdx.x;
  int idx = blockIdx.x*256 + tid;
  int c = (idx>>12)&63;              // constant per block
  __shared__ float sAB[2];
  __shared__ float w8[8];
  {
    float S = pin[c*256 + tid];
    float Q = pin[16384 + c*256 + tid];
    #pragma unroll
    for(int d=1; d<64; d<<=1){ S += __shfl_xor(S,d); Q += __shfl_xor(Q,d); }
    int wv = tid>>6, ln = tid&63;
    if(ln==0){ w8[wv] = S; w8[4+wv] = Q; }
    __syncthreads();
    if(tid==0){
      float Sa = (w8[0]+w8[1])+(w8[2]+w8[3]);
      float Qa = (w8[4]+w8[5])+(w8[6]+w8[7]);
      float m = Sa*(1.f/8192.f);
      float var = Qa*(1.f/8192.f) - m*m;
      float r = rsqrtf(var + EPSc);
      float gc = g3[c];
      sAB[0] = gc*r; sAB[1] = bb3[c] - m*gc*r;
    }
    __syncthreads();
  }
  float y = fmaf(ts[idx], sAB[0], sAB[1]);
  float al = ap[0];
  y = y >= 0.f ? y : al*y;
  h[idx] += y;
}

// ---- head v2: 1x1 conv (64->512) -> gvol [b][q][ci][k][o][z=p] ----
__global__ void k_head_t(const float* __restrict__ h, const float* __restrict__ w,
                         const float* __restrict__ bias, float* __restrict__ gv){
  __shared__ float lh[8*65];      // [p8][kc64]
  __shared__ float lw[64*65];     // [cc64][kc64]
  int bid = blockIdx.x;           // (b*64 + q)*8 + pgg
  int pgg = bid & 7, q = (bid>>3) & 63, b = bid >> 9;
  int tid = threadIdx.x;
  for(int t = tid; t < 512; t += 256){
    int p = t >> 6, kc = t & 63;
    lh[p*65 + kc] = h[((size_t)(b*64+kc))*SPc + (pgg*8+p)*64 + q];
  }
  int cc = tid & 63, pp = tid >> 6;     // wave-uniform pp
  float* gb = gv + (size_t)b*(64*16*2048) + ((size_t)q*16)*2048;
  for(int ch = 0; ch < 8; ++ch){
    __syncthreads();
    for(int t = tid; t < 1024; t += 256){
      int rc = t >> 4, f4 = t & 15;
      int combo = ch*64 + rc;
      int ci = combo>>5, kk = (combo>>4)&1, o = combo&15;
      int c0 = (o*16+ci)*2 + kk;
      float4 v = *(const float4*)(w + (size_t)c0*64 + f4*4);
      *(float4*)(&lw[rc*65 + f4*4]) = v;
    }
    __syncthreads();
    int combo = ch*64 + cc;
    int ci = combo>>5, kk = (combo>>4)&1, o = combo&15;
    int c0 = (o*16+ci)*2 + kk;
    float a0 = 0.f, a1 = 0.f;
    const float* lh0 = &lh[(pp*2+0)*65];
    const float* lh1 = &lh[(pp*2+1)*65];
    const float* lwr = &lw[cc*65];
    #pragma unroll 8
    for(int kc=0; kc<64; kc++){
      float wv = lwr[kc];
      a0 = fmaf(lh0[kc], wv, a0);
      a1 = fmaf(lh1[kc], wv, a1);
    }
    float bv = bias[c0];
    float* dst = gb + (size_t)ci*2048 + kk*1024 + o*64 + pgg*8 + pp*2;
    *(float2*)dst = make_float2(a0 + bv, a1 + bv);
  }
}

// ---- slice v5: 17-col segments, lane-transposed (16 lanes = 16 o, 1 px) ----
__global__ void k_slice(const float* __restrict__ x, const float* __restrict__ gv,
                        float* __restrict__ outp, float* __restrict__ pacc){
  __shared__ float lds[8320];     // 4160 float2
  int xseg = blockIdx.x, hp = blockIdx.y, b = blockIdx.z;
  int tid = threadIdx.x;
  const float* gb = gv + (size_t)b*(64*16*2048);
  int y0 = (hp*63)/255;
  int y1 = min(y0+1, 63);
  float fy = hp*(63.f/255.f) - (float)y0;

  if(tid < 128){
    int half = tid & 1, o = (tid>>1)&15, k = (tid>>5)&1, cix = (tid>>6)&1;
    int xs = min(xseg + cix, 15);
    const float* b0p = gb + (size_t)(y0*16+xs)*2048 + k*1024 + o*64;
    const float* b1p = gb + (size_t)(y1*16+xs)*2048 + k*1024 + o*64;
    float2* d = (float2*)lds + cix*2080 + k*1040 + o*65;
    float prev = 0.f;
    if(half){
      float a = b0p[31], c = b1p[31];
      prev = fmaf(fy, c-a, a);
    }
    int j0 = half*8;
    #pragma unroll
    for(int j=0; j<8; ++j){
      int jj = j0 + j;
      float4 a = *(const float4*)(b0p + jj*4);
      float4 c = *(const float4*)(b1p + jj*4);
      float v0 = fmaf(fy, c.x-a.x, a.x);
      float v1 = fmaf(fy, c.y-a.y, a.y);
      float v2 = fmaf(fy, c.z-a.z, a.z);
      float v3 = fmaf(fy, c.w-a.w, a.w);
      if(j > 0 || half) d[4*jj-1] = make_float2(prev, v0);
      d[4*jj]   = make_float2(v0, v1);
      d[4*jj+1] = make_float2(v1, v2);
      d[4*jj+2] = make_float2(v2, v3);
      prev = v3;
    }
    if(half) d[63] = make_float2(prev, prev);
  }
  __syncthreads();

  int wv = tid>>6, lane = tid&63;
  int o = lane & 15, pl = lane >> 4;  // 16 lanes = 16 o of ONE pixel
  int lc = wv*4 + pl;                 // 0..19 (17+ invalid)
  int wq = xseg*17 + lc;
  bool act = (lc < 17) && (wq < 256);
  int wqc = min(wq, 255);

  float fx = (float)lc * (1.f/17.f);
  float cwA = 1.f - fx, cwB = fx;
  int obase = o*65;
  const float2* l2 = (const float2*)lds;

  float acc = 0.f, bacc = 0.f;
  for(int i=0; i<CIc; i++){
    float xv = x[((size_t)(b*CIc+i)*Hc + hp)*Wc + wqc];
    float g = fminf(fmaxf(xv, 0.f), 1.f);
    float pz = g*63.f;
    int z0 = (int)pz; float fz = pz - (float)z0;
    float wz0 = cwA*(1.f-fz), wz1 = cwA*fz;
    float vz0 = cwB*(1.f-fz), vz1 = cwB*fz;
    int aA = obase + z0, aB = 2080 + obase + z0;
    float2 wA = l2[aA],        wB = l2[aB];
    float2 bA = l2[aA + 1040], bB = l2[aB + 1040];
    float wsum = fmaf(wz0, wA.x, fmaf(wz1, wA.y, fmaf(vz0, wB.x, vz1*wB.y)));
    float bsum = fmaf(wz0, bA.x, fmaf(wz1, bA.y, fmaf(vz0, bB.x, vz1*bB.y)));
    acc  = fmaf(xv, wsum, acc);
    bacc += bsum;
  }
  float vout = act ? (acc + bacc*(1.f/16.f)) : 0.f;
  if(act)
    outp[((size_t)(b*COc+o)*Hc + hp)*Wc + wq] = vout;

  float sm = vout, sq = vout*vout;
  sm += __shfl_xor(sm,16); sq += __shfl_xor(sq,16);
  sm += __shfl_xor(sm,32); sq += __shfl_xor(sq,32);
  __syncthreads();
  if(lane < 16){ lds[(wv*16+o)*2] = sm; lds[(wv*16+o)*2+1] = sq; }
  __syncthreads();
  if(tid < 32){
    int oo = tid>>1, kd = tid&1;
    float S = (((lds[(0*16+oo)*2+kd] + lds[(1*16+oo)*2+kd])
             +  (lds[(2*16+oo)*2+kd] + lds[(3*16+oo)*2+kd]))
             +   lds[(4*16+oo)*2+kd]);
    int blk = (b*256 + hp)*16 + xseg;       // P=8192
    pacc[kd*131072 + oo*8192 + blk] = S;    // CP = 16*8192
  }
}

// ---- final BN + SiLU in place on d_out ----
__global__ void k_final(float* __restrict__ out, const float* __restrict__ A,
                        const float* __restrict__ B){
  int idx = blockIdx.x*256 + threadIdx.x;
  int c = (idx>>16)&15;
  float y = fmaf(out[idx], A[c], B[c]);
  out[idx] = y / (1.f + expf(-y));
}

} // namespace

extern "C" void kernel_launch(void* const* d_in, const int* in_sizes, int n_in,
                              void* d_out, int out_size, void* d_ws, size_t ws_size,
                              hipStream_t stream){
  const float* x       = (const float*)d_in[0];
  const float* conv0_w = (const float*)d_in[1];
  const float* conv0_b = (const float*)d_in[2];
  const float* prelu0  = (const float*)d_in[3];
  const float* c1w  = (const float*)d_in[4];
  const float* c1b  = (const float*)d_in[5];
  const float* bn1g = (const float*)d_in[6];
  const float* bn1b = (const float*)d_in[7];
  const float* p1   = (const float*)d_in[8];
  const float* dww  = (const float*)d_in[9];
  const float* dwb  = (const float*)d_in[10];
  const float* bn2g = (const float*)d_in[11];
  const float* bn2b = (const float*)d_in[12];
  const float* p2   = (const float*)d_in[13];
  const float* c3w  = (const float*)d_in[14];
  const float* c3b  = (const float*)d_in[15];
  const float* bn3g = (const float*)d_in[16];
  const float* bn3b = (const float*)d_in[17];
  const float* p3   = (const float*)d_in[18];
  const float* hw   = (const float*)d_in[19];
  const float* hb   = (const float*)d_in[20];
  const float* obg  = (const float*)d_in[21];
  const float* obb  = (const float*)d_in[22];
  float* out = (float*)d_out;
  float* ws  = (float*)d_ws;

  // workspace (floats)
  float* xd    = ws;                 // 131072
  float* h     = xd + 131072;        // 524288
  float* A     = h  + 524288;        // 320
  float* B     = A  + 320;           // 320
  float* pacc  = B  + 320;           // 81920  BN1 partials
  float* paccb = pacc + 81920;       // 20480  BN2 partials (P=2 uses first 1280)
  float* paccc = paccb + 20480;      // 65536  BN3 partials
  float* t1    = paccc + 65536;      // 2621440
  float* t2    = t1 + 2621440;       // 2621440
  float* ts    = t2 + 2621440;       // 524288
  float* gv    = t1;                 // 4194304 aliases t1+t2 (dead by head)
  float* pacc2 = ts;                 // 262144 slice partials alias ts

  k_down <<<512,  256, 0, stream>>>(x, xd);
  k_conv0<<<512, 256, 0, stream>>>(xd, conv0_w, conv0_b, prelu0, h);

  for(int i=0; i<3; i++){
    k_c1  <<<dim3(4,64,Bn), 256, 0, stream>>>(h, c1w + i*20480, c1b + i*320, t1, pacc);
    k_dw_s<<<640, 256, 0, stream>>>(t1, dww + i*2880, dwb + i*320,
                                    bn1g+i*320, bn1b+i*320, p1+i, pacc, t2, paccb);
    k_c3f <<<dim3(128,Bn), 256, 0, stream>>>(t2, c3w + i*20480, c3b + i*64,
                                             bn2g+i*320, bn2b+i*320, p2+i, paccb, ts, paccc);
    k_addres<<<2048, 256, 0, stream>>>(ts, h, bn3g+i*64, bn3b+i*64, p3+i, paccc);
  }

  k_head_t<<<1024, 256, 0, stream>>>(h, hw, hb, gv);
  k_slice <<<dim3(16,256,Bn), 320, 0, stream>>>(x, gv, out, pacc2);
  k_fin   <<<16, 256, 0, stream>>>(pacc2, 8192, 1.f/131072.f, obg, obb, A, B);
  k_final <<<8192, 256, 0, stream>>>(out, A, B);
}

// Round 32
// 274.586 us; speedup vs baseline: 1.6362x; 1.0245x over previous
//
#include <hip/hip_runtime.h>
#include <math.h>

namespace {

constexpr int Bn=2, CIc=16, COc=16, Hc=256, Wc=256, HIDc=64, C5c=320;
constexpr int SPc = 4096;               // 64*64
constexpr float EPSc = 1e-5f;

// ---- 4x4 mean downsample: x (B,16,256,256) -> xd (B,16,64,64) ----
__global__ void k_down(const float* __restrict__ x, float* __restrict__ xd){
  int idx = blockIdx.x*blockDim.x + threadIdx.x;
  if (idx >= Bn*CIc*SPc) return;
  int q = idx & 63, p = (idx>>6)&63, c = idx>>12;
  const float* xp = x + ((size_t)c*Hc + p*4)*Wc + q*4;
  float s = 0.f;
  #pragma unroll
  for(int dy=0; dy<4; dy++)
    #pragma unroll
    for(int dx=0; dx<4; dx++) s += xp[dy*Wc+dx];
  xd[idx] = s * (1.f/16.f);
}

// ---- conv0 v2: 3x3 pad1 (16->64) + PReLU, 4-px register tile ----
__global__ void k_conv0(const float* __restrict__ xd, const float* __restrict__ w,
                        const float* __restrict__ bias, const float* __restrict__ a0,
                        float* __restrict__ h){
  int idx = blockIdx.x*blockDim.x + threadIdx.x;   // 131072 total
  int qg = idx & 15, p = (idx>>4)&63, co = (idx>>10)&63, b = idx>>16;
  int q0 = qg*4;
  float acc0, acc1, acc2, acc3;
  float bv = bias[co];
  acc0 = acc1 = acc2 = acc3 = bv;
  for(int ci=0; ci<CIc; ci++){
    const float* xp = xd + (size_t)(b*CIc+ci)*SPc;
    const float* wp = w + (co*CIc+ci)*9;
    #pragma unroll
    for(int u=0; u<3; u++){
      int pp = p+u-1;
      if((unsigned)pp >= 64u) continue;
      const float* xr = xp + pp*64;
      float4 m = *(const float4*)(xr + q0);
      float lft = (q0 > 0)  ? xr[q0-1] : 0.f;
      float rgt = (q0 < 60) ? xr[q0+4] : 0.f;
      float w0 = wp[u*3+0], w1 = wp[u*3+1], w2 = wp[u*3+2];
      acc0 = fmaf(lft, w0, acc0); acc0 = fmaf(m.x, w1, acc0); acc0 = fmaf(m.y, w2, acc0);
      acc1 = fmaf(m.x, w0, acc1); acc1 = fmaf(m.y, w1, acc1); acc1 = fmaf(m.z, w2, acc1);
      acc2 = fmaf(m.y, w0, acc2); acc2 = fmaf(m.z, w1, acc2); acc2 = fmaf(m.w, w2, acc2);
      acc3 = fmaf(m.z, w0, acc3); acc3 = fmaf(m.w, w1, acc3); acc3 = fmaf(rgt, w2, acc3);
    }
  }
  float a = a0[0];
  float4 o4;
  o4.x = acc0 >= 0.f ? acc0 : a*acc0;
  o4.y = acc1 >= 0.f ? acc1 : a*acc1;
  o4.z = acc2 >= 0.f ? acc2 : a*acc2;
  o4.w = acc3 >= 0.f ? acc3 : a*acc3;
  *(float4*)(h + (size_t)(b*HIDc+co)*SPc + p*64 + q0) = o4;
}

// ---- fused 1x1 conv 64->320 + BN1 stat partials; 4s x 5o register tile ----
__global__ void k_c1(const float* __restrict__ h, const float* __restrict__ w,
                     const float* __restrict__ bias, float* __restrict__ t1,
                     float* __restrict__ pacc){
  __shared__ float lh[64*64];
  int og = blockIdx.x, sj = blockIdx.y, b = blockIdx.z;
  int tid = threadIdx.x;
  for(int it=0; it<4; ++it){
    int f4 = tid + it*256;               // c*16 + s4
    int c = f4>>4, s4 = f4&15;
    float4 v = *(const float4*)(h + (size_t)(b*64+c)*SPc + sj*64 + s4*4);
    *(float4*)(&lh[c*64 + s4*4]) = v;
  }
  __syncthreads();
  int sq = tid & 15, oj = tid >> 4;
  int ob = og*80 + oj*5;
  float acc[4][5];
  #pragma unroll
  for(int k=0;k<4;k++)
    #pragma unroll
    for(int j=0;j<5;j++) acc[k][j] = 0.f;
  const float* lhs = lh + sq*4;
  for(int c=0;c<64;c++){
    float h0 = lhs[c*64+0];
    float h1 = lhs[c*64+1];
    float h2 = lhs[c*64+2];
    float h3 = lhs[c*64+3];
    #pragma unroll
    for(int j=0;j<5;j++){
      float wv = w[(ob+j)*64 + c];
      acc[0][j] = fmaf(h0, wv, acc[0][j]);
      acc[1][j] = fmaf(h1, wv, acc[1][j]);
      acc[2][j] = fmaf(h2, wv, acc[2][j]);
      acc[3][j] = fmaf(h3, wv, acc[3][j]);
    }
  }
  #pragma unroll
  for(int j=0;j<5;j++){
    int o = ob + j;
    float bv = bias[o];
    float4 v4 = make_float4(acc[0][j]+bv, acc[1][j]+bv, acc[2][j]+bv, acc[3][j]+bv);
    *(float4*)(t1 + (size_t)(b*320+o)*SPc + sj*64 + sq*4) = v4;
    float sm  = (v4.x+v4.y)+(v4.z+v4.w);
    float sq2 = (v4.x*v4.x + v4.y*v4.y) + (v4.z*v4.z + v4.w*v4.w);
    sm += __shfl_xor(sm,1); sq2 += __shfl_xor(sq2,1);
    sm += __shfl_xor(sm,2); sq2 += __shfl_xor(sq2,2);
    sm += __shfl_xor(sm,4); sq2 += __shfl_xor(sq2,4);
    sm += __shfl_xor(sm,8); sq2 += __shfl_xor(sq2,8);
    if(sq==0){
      pacc[o*128 + b*64 + sj]         = sm;   // P=128
      pacc[40960 + o*128 + b*64 + sj] = sq2;  // CP = 320*128
    }
  }
}

// ---- finalize (out-BN only): partials -> A,B ----
__global__ void k_fin(const float* __restrict__ pacc, int P, float invN,
                      const float* __restrict__ g, const float* __restrict__ bb,
                      float* __restrict__ A, float* __restrict__ B){
  __shared__ double sh[256], sh2[256];
  int c = blockIdx.x, C = gridDim.x, tid = threadIdx.x;
  double s=0.0, s2=0.0;
  for(int p=tid; p<P; p+=256){
    s  += (double)pacc[c*P+p];
    s2 += (double)pacc[C*P + c*P + p];
  }
  sh[tid]=s; sh2[tid]=s2; __syncthreads();
  for(int off=128; off>0; off>>=1){
    if(tid<off){ sh[tid]+=sh[tid+off]; sh2[tid]+=sh2[tid+off]; }
    __syncthreads();
  }
  if(tid==0){
    float m = (float)(sh[0]*(double)invN);
    float v = (float)(sh2[0]*(double)invN) - m*m;
    float r = rsqrtf(v + EPSc);
    float gc = g[c];
    A[c] = gc*r;
    B[c] = bb[c] - m*gc*r;
  }
}

// ---- depthwise 3x3 v2: one (b,c) 64x64 plane per block, LDS-tiled ----
__global__ void k_dw_s(const float* __restrict__ t1, const float* __restrict__ w,
                       const float* __restrict__ bias, const float* __restrict__ g1,
                       const float* __restrict__ bb1, const float* __restrict__ ap,
                       const float* __restrict__ pin, float* __restrict__ t2,
                       float* __restrict__ pout){
  __shared__ float lt[64*65];     // padded plane, 16.25 KB
  int bid = blockIdx.x;
  int c = bid % C5c, b = bid / C5c;
  int tid = threadIdx.x;
  __shared__ float sAB[2];
  __shared__ float ws4[4];
  {
    float v = (tid<128) ? pin[c*128 + tid] : pin[40960 + c*128 + (tid-128)];
    #pragma unroll
    for(int d=1; d<64; d<<=1) v += __shfl_xor(v, d);
    int wv = tid>>6, ln = tid&63;
    if(ln==0) ws4[wv] = v;
    __syncthreads();
    if(tid==0){
      float S = ws4[0]+ws4[1], Q = ws4[2]+ws4[3];
      float m = S*(1.f/8192.f);
      float var = Q*(1.f/8192.f) - m*m;
      float r = rsqrtf(var + EPSc);
      float gc = g1[c];
      sAB[0] = gc*r; sAB[1] = bb1[c] - m*gc*r;
    }
    __syncthreads();
  }
  float a1 = sAB[0], b1 = sAB[1], al = ap[0];
  const float* ip = t1 + (size_t)(b*C5c+c)*SPc;
  for(int t = tid; t < 1024; t += 256){
    int p = t >> 4, f4 = t & 15;
    float4 v = *(const float4*)(ip + p*64 + f4*4);
    float4 y;
    y.x = fmaf(v.x, a1, b1); y.x = y.x>=0.f ? y.x : al*y.x;
    y.y = fmaf(v.y, a1, b1); y.y = y.y>=0.f ? y.y : al*y.y;
    y.z = fmaf(v.z, a1, b1); y.z = y.z>=0.f ? y.z : al*y.z;
    y.w = fmaf(v.w, a1, b1); y.w = y.w>=0.f ? y.w : al*y.w;
    *(float4*)(&lt[p*65 + f4*4]) = y;
  }
  const float* wp = w + c*9;
  float w00=wp[0], w01=wp[1], w02=wp[2],
        w10=wp[3], w11=wp[4], w12=wp[5],
        w20=wp[6], w21=wp[7], w22=wp[8];
  float bv = bias[c];
  __syncthreads();
  int r0 = (tid >> 4) * 4, q0 = (tid & 15) * 4;
  float sm = 0.f, sq2 = 0.f;
  float* op = t2 + (size_t)(b*C5c+c)*SPc;
  #pragma unroll
  for(int dr=0; dr<4; ++dr){
    int p = r0 + dr;
    #pragma unroll
    for(int dq=0; dq<4; ++dq){
      int q = q0 + dq;
      float acc = bv;
      #pragma unroll
      for(int u=0; u<3; u++){
        int pp = p+u-1; if((unsigned)pp >= 64u) continue;
        const float* lr = &lt[pp*65];
        float wr0 = (u==0)?w00:(u==1)?w10:w20;
        float wr1 = (u==0)?w01:(u==1)?w11:w21;
        float wr2 = (u==0)?w02:(u==1)?w12:w22;
        if(q >= 1)  acc = fmaf(lr[q-1], wr0, acc);
        acc = fmaf(lr[q], wr1, acc);
        if(q <= 62) acc = fmaf(lr[q+1], wr2, acc);
      }
      op[p*64 + q] = acc;
      sm += acc; sq2 += acc*acc;
    }
  }
  #pragma unroll
  for(int d=1; d<64; d<<=1){ sm += __shfl_xor(sm,d); sq2 += __shfl_xor(sq2,d); }
  __shared__ float sred[8];
  int wv = tid>>6, ln = tid&63;
  if(ln==0){ sred[wv]=sm; sred[4+wv]=sq2; }
  __syncthreads();
  if(tid==0){
    float S = ((sred[0]+sred[1])+(sred[2]+sred[3]));
    float Q = ((sred[4]+sred[5])+(sred[6]+sred[7]));
    pout[c*2 + b]       = S;   // P=2
    pout[640 + c*2 + b] = Q;   // CP = 320*2
  }
}

// ---- full-K 1x1 conv 320->64 v3: 32 px/block, og-split (2 blocks/CU) ----
// grid (128 sjf, 2 og, Bn), 256 thr = 16 oj x 16 sq; thread = 2px x 2outs.
__global__ void k_c3f(const float* __restrict__ t2, const float* __restrict__ w,
                      const float* __restrict__ bias, const float* __restrict__ g2,
                      const float* __restrict__ bb2, const float* __restrict__ ap,
                      const float* __restrict__ pin, float* __restrict__ ts,
                      float* __restrict__ pout){
  __shared__ float sA[320], sB[320];
  __shared__ float li[320*32];    // 40 KB
  int sjf = blockIdx.x, og = blockIdx.y, b = blockIdx.z;
  int tid = threadIdx.x;
  for(int c = tid; c < 320; c += 256){
    float S = pin[c*2] + pin[c*2+1];
    float Q = pin[640 + c*2] + pin[640 + c*2+1];
    float m = S*(1.f/8192.f);
    float var = Q*(1.f/8192.f) - m*m;
    float r = rsqrtf(var + EPSc);
    float gc = g2[c];
    sA[c] = gc*r; sB[c] = bb2[c] - m*gc*r;
  }
  __syncthreads();
  float al = ap[0];
  for(int t = tid; t < 2560; t += 256){
    int c = t>>3, f8 = t&7;
    float4 v = *(const float4*)(t2 + (size_t)(b*C5c+c)*SPc + sjf*32 + f8*4);
    float a1 = sA[c], b1 = sB[c];
    float4 y;
    y.x = fmaf(v.x, a1, b1); y.x = y.x>=0.f ? y.x : al*y.x;
    y.y = fmaf(v.y, a1, b1); y.y = y.y>=0.f ? y.y : al*y.y;
    y.z = fmaf(v.z, a1, b1); y.z = y.z>=0.f ? y.z : al*y.z;
    y.w = fmaf(v.w, a1, b1); y.w = y.w>=0.f ? y.w : al*y.w;
    *(float4*)(&li[c*32 + f8*4]) = y;
  }
  __syncthreads();
  int sq = tid & 15, oj = tid >> 4;   // 2 px per sq, 2 outs per oj
  int ob = og*32 + oj*2;
  float acc[2][2];
  acc[0][0]=acc[0][1]=acc[1][0]=acc[1][1]=0.f;
  const float* wb = w + (size_t)ob*C5c;
  const float* lis = li + sq*2;
  for(int c=0; c<320; c++){
    float h0 = lis[c*32];
    float h1 = lis[c*32+1];
    float w0 = wb[c];
    float w1 = wb[C5c + c];
    acc[0][0] = fmaf(h0, w0, acc[0][0]);
    acc[1][0] = fmaf(h1, w0, acc[1][0]);
    acc[0][1] = fmaf(h0, w1, acc[0][1]);
    acc[1][1] = fmaf(h1, w1, acc[1][1]);
  }
  #pragma unroll
  for(int j=0;j<2;j++){
    int o = ob + j;
    float bv = bias[o];
    float v0 = acc[0][j]+bv, v1 = acc[1][j]+bv;
    *(float2*)(ts + (size_t)(b*64+o)*SPc + sjf*32 + sq*2) = make_float2(v0, v1);
    float sm = v0+v1, sq2 = v0*v0 + v1*v1;
    sm += __shfl_xor(sm,1); sq2 += __shfl_xor(sq2,1);
    sm += __shfl_xor(sm,2); sq2 += __shfl_xor(sq2,2);
    sm += __shfl_xor(sm,4); sq2 += __shfl_xor(sq2,4);
    sm += __shfl_xor(sm,8); sq2 += __shfl_xor(sq2,8);
    if(sq==0){
      pout[o*256 + b*128 + sjf]         = sm;   // P=256
      pout[16384 + o*256 + b*128 + sjf] = sq2;  // CP = 64*256
    }
  }
}

// ---- BN3 (finalized in prologue, P=256) + PReLU3 + residual add into h ----
__global__ void k_addres(const float* __restrict__ ts, float* __restrict__ h,
                         const float* __restrict__ g3, const float* __restrict__ bb3,
                         const float* __restrict__ ap, const float* __restrict__ pin){
  int tid = threadIdx.x;
  int idx = blockIdx.x*256 + tid;
  int c = (idx>>12)&63;              // constant per block
  __shared__ float sAB[2];
  __shared__ float w8[8];
  {
    float S = pin[c*256 + tid];
    float Q = pin[16384 + c*256 + tid];
    #pragma unroll
    for(int d=1; d<64; d<<=1){ S += __shfl_xor(S,d); Q += __shfl_xor(Q,d); }
    int wv = tid>>6, ln = tid&63;
    if(ln==0){ w8[wv] = S; w8[4+wv] = Q; }
    __syncthreads();
    if(tid==0){
      float Sa = (w8[0]+w8[1])+(w8[2]+w8[3]);
      float Qa = (w8[4]+w8[5])+(w8[6]+w8[7]);
      float m = Sa*(1.f/8192.f);
      float var = Qa*(1.f/8192.f) - m*m;
      float r = rsqrtf(var + EPSc);
      float gc = g3[c];
      sAB[0] = gc*r; sAB[1] = bb3[c] - m*gc*r;
    }
    __syncthreads();
  }
  float y = fmaf(ts[idx], sAB[0], sAB[1]);
  float al = ap[0];
  y = y >= 0.f ? y : al*y;
  h[idx] += y;
}

// ---- head v2: 1x1 conv (64->512) -> gvol [b][q][ci][k][o][z=p] ----
__global__ void k_head_t(const float* __restrict__ h, const float* __restrict__ w,
                         const float* __restrict__ bias, float* __restrict__ gv){
  __shared__ float lh[8*65];      // [p8][kc64]
  __shared__ float lw[64*65];     // [cc64][kc64]
  int bid = blockIdx.x;           // (b*64 + q)*8 + pgg
  int pgg = bid & 7, q = (bid>>3) & 63, b = bid >> 9;
  int tid = threadIdx.x;
  for(int t = tid; t < 512; t += 256){
    int p = t >> 6, kc = t & 63;
    lh[p*65 + kc] = h[((size_t)(b*64+kc))*SPc + (pgg*8+p)*64 + q];
  }
  int cc = tid & 63, pp = tid >> 6;     // wave-uniform pp
  float* gb = gv + (size_t)b*(64*16*2048) + ((size_t)q*16)*2048;
  for(int ch = 0; ch < 8; ++ch){
    __syncthreads();
    for(int t = tid; t < 1024; t += 256){
      int rc = t >> 4, f4 = t & 15;
      int combo = ch*64 + rc;
      int ci = combo>>5, kk = (combo>>4)&1, o = combo&15;
      int c0 = (o*16+ci)*2 + kk;
      float4 v = *(const float4*)(w + (size_t)c0*64 + f4*4);
      *(float4*)(&lw[rc*65 + f4*4]) = v;
    }
    __syncthreads();
    int combo = ch*64 + cc;
    int ci = combo>>5, kk = (combo>>4)&1, o = combo&15;
    int c0 = (o*16+ci)*2 + kk;
    float a0 = 0.f, a1 = 0.f;
    const float* lh0 = &lh[(pp*2+0)*65];
    const float* lh1 = &lh[(pp*2+1)*65];
    const float* lwr = &lw[cc*65];
    #pragma unroll 8
    for(int kc=0; kc<64; kc++){
      float wv = lwr[kc];
      a0 = fmaf(lh0[kc], wv, a0);
      a1 = fmaf(lh1[kc], wv, a1);
    }
    float bv = bias[c0];
    float* dst = gb + (size_t)ci*2048 + kk*1024 + o*64 + pgg*8 + pp*2;
    *(float2*)dst = make_float2(a0 + bv, a1 + bv);
  }
}

// ---- slice v5: 17-col segments, lane-transposed (16 lanes = 16 o, 1 px) ----
__global__ void k_slice(const float* __restrict__ x, const float* __restrict__ gv,
                        float* __restrict__ outp, float* __restrict__ pacc){
  __shared__ float lds[8320];     // 4160 float2
  int xseg = blockIdx.x, hp = blockIdx.y, b = blockIdx.z;
  int tid = threadIdx.x;
  const float* gb = gv + (size_t)b*(64*16*2048);
  int y0 = (hp*63)/255;
  int y1 = min(y0+1, 63);
  float fy = hp*(63.f/255.f) - (float)y0;

  if(tid < 128){
    int half = tid & 1, o = (tid>>1)&15, k = (tid>>5)&1, cix = (tid>>6)&1;
    int xs = min(xseg + cix, 15);
    const float* b0p = gb + (size_t)(y0*16+xs)*2048 + k*1024 + o*64;
    const float* b1p = gb + (size_t)(y1*16+xs)*2048 + k*1024 + o*64;
    float2* d = (float2*)lds + cix*2080 + k*1040 + o*65;
    float prev = 0.f;
    if(half){
      float a = b0p[31], c = b1p[31];
      prev = fmaf(fy, c-a, a);
    }
    int j0 = half*8;
    #pragma unroll
    for(int j=0; j<8; ++j){
      int jj = j0 + j;
      float4 a = *(const float4*)(b0p + jj*4);
      float4 c = *(const float4*)(b1p + jj*4);
      float v0 = fmaf(fy, c.x-a.x, a.x);
      float v1 = fmaf(fy, c.y-a.y, a.y);
      float v2 = fmaf(fy, c.z-a.z, a.z);
      float v3 = fmaf(fy, c.w-a.w, a.w);
      if(j > 0 || half) d[4*jj-1] = make_float2(prev, v0);
      d[4*jj]   = make_float2(v0, v1);
      d[4*jj+1] = make_float2(v1, v2);
      d[4*jj+2] = make_float2(v2, v3);
      prev = v3;
    }
    if(half) d[63] = make_float2(prev, prev);
  }
  __syncthreads();

  int wv = tid>>6, lane = tid&63;
  int o = lane & 15, pl = lane >> 4;  // 16 lanes = 16 o of ONE pixel
  int lc = wv*4 + pl;                 // 0..19 (17+ invalid)
  int wq = xseg*17 + lc;
  bool act = (lc < 17) && (wq < 256);
  int wqc = min(wq, 255);

  float fx = (float)lc * (1.f/17.f);
  float cwA = 1.f - fx, cwB = fx;
  int obase = o*65;
  const float2* l2 = (const float2*)lds;

  float acc = 0.f, bacc = 0.f;
  for(int i=0; i<CIc; i++){
    float xv = x[((size_t)(b*CIc+i)*Hc + hp)*Wc + wqc];
    float g = fminf(fmaxf(xv, 0.f), 1.f);
    float pz = g*63.f;
    int z0 = (int)pz; float fz = pz - (float)z0;
    float wz0 = cwA*(1.f-fz), wz1 = cwA*fz;
    float vz0 = cwB*(1.f-fz), vz1 = cwB*fz;
    int aA = obase + z0, aB = 2080 + obase + z0;
    float2 wA = l2[aA],        wB = l2[aB];
    float2 bA = l2[aA + 1040], bB = l2[aB + 1040];
    float wsum = fmaf(wz0, wA.x, fmaf(wz1, wA.y, fmaf(vz0, wB.x, vz1*wB.y)));
    float bsum = fmaf(wz0, bA.x, fmaf(wz1, bA.y, fmaf(vz0, bB.x, vz1*bB.y)));
    acc  = fmaf(xv, wsum, acc);
    bacc += bsum;
  }
  float vout = act ? (acc + bacc*(1.f/16.f)) : 0.f;
  if(act)
    outp[((size_t)(b*COc+o)*Hc + hp)*Wc + wq] = vout;

  float sm = vout, sq = vout*vout;
  sm += __shfl_xor(sm,16); sq += __shfl_xor(sq,16);
  sm += __shfl_xor(sm,32); sq += __shfl_xor(sq,32);
  __syncthreads();
  if(lane < 16){ lds[(wv*16+o)*2] = sm; lds[(wv*16+o)*2+1] = sq; }
  __syncthreads();
  if(tid < 32){
    int oo = tid>>1, kd = tid&1;
    float S = (((lds[(0*16+oo)*2+kd] + lds[(1*16+oo)*2+kd])
             +  (lds[(2*16+oo)*2+kd] + lds[(3*16+oo)*2+kd]))
             +   lds[(4*16+oo)*2+kd]);
    int blk = (b*256 + hp)*16 + xseg;       // P=8192
    pacc[kd*131072 + oo*8192 + blk] = S;    // CP = 16*8192
  }
}

// ---- final BN + SiLU in place on d_out ----
__global__ void k_final(float* __restrict__ out, const float* __restrict__ A,
                        const float* __restrict__ B){
  int idx = blockIdx.x*256 + threadIdx.x;
  int c = (idx>>16)&15;
  float y = fmaf(out[idx], A[c], B[c]);
  out[idx] = y / (1.f + expf(-y));
}

} // namespace

extern "C" void kernel_launch(void* const* d_in, const int* in_sizes, int n_in,
                              void* d_out, int out_size, void* d_ws, size_t ws_size,
                              hipStream_t stream){
  const float* x       = (const float*)d_in[0];
  const float* conv0_w = (const float*)d_in[1];
  const float* conv0_b = (const float*)d_in[2];
  const float* prelu0  = (const float*)d_in[3];
  const float* c1w  = (const float*)d_in[4];
  const float* c1b  = (const float*)d_in[5];
  const float* bn1g = (const float*)d_in[6];
  const float* bn1b = (const float*)d_in[7];
  const float* p1   = (const float*)d_in[8];
  const float* dww  = (const float*)d_in[9];
  const float* dwb  = (const float*)d_in[10];
  const float* bn2g = (const float*)d_in[11];
  const float* bn2b = (const float*)d_in[12];
  const float* p2   = (const float*)d_in[13];
  const float* c3w  = (const float*)d_in[14];
  const float* c3b  = (const float*)d_in[15];
  const float* bn3g = (const float*)d_in[16];
  const float* bn3b = (const float*)d_in[17];
  const float* p3   = (const float*)d_in[18];
  const float* hw   = (const float*)d_in[19];
  const float* hb   = (const float*)d_in[20];
  const float* obg  = (const float*)d_in[21];
  const float* obb  = (const float*)d_in[22];
  float* out = (float*)d_out;
  float* ws  = (float*)d_ws;

  // workspace (floats)
  float* xd    = ws;                 // 131072
  float* h     = xd + 131072;        // 524288
  float* A     = h  + 524288;        // 320
  float* B     = A  + 320;           // 320
  float* pacc  = B  + 320;           // 81920  BN1 partials
  float* paccb = pacc + 81920;       // 20480  BN2 partials (P=2 uses first 1280)
  float* paccc = paccb + 20480;      // 65536  BN3 partials
  float* t1    = paccc + 65536;      // 2621440
  float* t2    = t1 + 2621440;       // 2621440
  float* ts    = t2 + 2621440;       // 524288
  float* gv    = t1;                 // 4194304 aliases t1+t2 (dead by head)
  float* pacc2 = ts;                 // 262144 slice partials alias ts

  k_down <<<512,  256, 0, stream>>>(x, xd);
  k_conv0<<<512, 256, 0, stream>>>(xd, conv0_w, conv0_b, prelu0, h);

  for(int i=0; i<3; i++){
    k_c1  <<<dim3(4,64,Bn), 256, 0, stream>>>(h, c1w + i*20480, c1b + i*320, t1, pacc);
    k_dw_s<<<640, 256, 0, stream>>>(t1, dww + i*2880, dwb + i*320,
                                    bn1g+i*320, bn1b+i*320, p1+i, pacc, t2, paccb);
    k_c3f <<<dim3(128,2,Bn), 256, 0, stream>>>(t2, c3w + i*20480, c3b + i*64,
                                               bn2g+i*320, bn2b+i*320, p2+i, paccb, ts, paccc);
    k_addres<<<2048, 256, 0, stream>>>(ts, h, bn3g+i*64, bn3b+i*64, p3+i, paccc);
  }

  k_head_t<<<1024, 256, 0, stream>>>(h, hw, hb, gv);
  k_slice <<<dim3(16,256,Bn), 320, 0, stream>>>(x, gv, out, pacc2);
  k_fin   <<<16, 256, 0, stream>>>(pacc2, 8192, 1.f/131072.f, obg, obb, A, B);
  k_final <<<8192, 256, 0, stream>>>(out, A, B);
}